// Round 14
// baseline (11119.626 us; speedup 1.0000x reference)
//
#include <hip/hip_runtime.h>

#define B_ROWS 8192
#define D_INN  2048
#define N_COL  16384
#define P_BASE 1024
#define L_LAT  600000
#define KC_BLK 18   // kc = 288 — fixes site A; np bits are kc288-class

// ---------------------------------------------------------------------------
// Faithful transcription of numpy npysort aquicksort (introsort, argsort
// variant) with comparator LT(a,b) := (b < a)  — i.e. exactly
// np.argsort(-x, kind='quicksort'): tosort ends DESCENDING in v with numpy's
// exact unstable tie behavior.  SMALL_QUICKSORT=15, median-of-3, Hoare
// partition, insertion leaves.  Heapsort depth fallback unreachable here.
// ---------------------------------------------------------------------------
#define NPY_LT(a, b) ((b) < (a))   // negated-value compare
__device__ void npy_aqs_desc(const float* __restrict__ v, int* tosort, int n)
{
    const int SMALL = 15;
    int stack[64]; int sp = 0;
    int pl = 0, pr = n - 1;
    for (;;) {
        while (pr - pl > SMALL) {
            const int pm = pl + ((pr - pl) >> 1);
            if (NPY_LT(v[tosort[pm]], v[tosort[pl]])) { int t = tosort[pm]; tosort[pm] = tosort[pl]; tosort[pl] = t; }
            if (NPY_LT(v[tosort[pr]], v[tosort[pm]])) { int t = tosort[pr]; tosort[pr] = tosort[pm]; tosort[pm] = t; }
            if (NPY_LT(v[tosort[pm]], v[tosort[pl]])) { int t = tosort[pm]; tosort[pm] = tosort[pl]; tosort[pl] = t; }
            const float vp = v[tosort[pm]];
            int pi = pl;
            int pj = pr - 1;
            { int t = tosort[pm]; tosort[pm] = tosort[pj]; tosort[pj] = t; }
            for (;;) {
                do { ++pi; } while (NPY_LT(v[tosort[pi]], vp));
                do { --pj; } while (NPY_LT(vp, v[tosort[pj]]));
                if (pi >= pj) break;
                int t = tosort[pi]; tosort[pi] = tosort[pj]; tosort[pj] = t;
            }
            const int pk = pr - 1;
            { int t = tosort[pi]; tosort[pi] = tosort[pk]; tosort[pk] = t; }
            if (pi - pl < pr - pi) { stack[sp++] = pi + 1; stack[sp++] = pr;     pr = pi - 1; }
            else                   { stack[sp++] = pl;     stack[sp++] = pi - 1; pl = pi + 1; }
        }
        for (int i = pl + 1; i <= pr; ++i) {   // stable insertion on leaf
            const int vi = tosort[i];
            const float vp = v[vi];
            int j = i;
            while (j > pl && NPY_LT(vp, v[tosort[j - 1]])) { tosort[j] = tosort[j - 1]; --j; }
            tosort[j] = vi;
        }
        if (sp == 0) break;
        pr = stack[--sp]; pl = stack[--sp];
    }
}

// ---------------------------------------------------------------------------
// Kernel 1: f32 GEMM  xs = x @ W^T + b  (kc=288 blocked tree, FMA in panel,
// panels folded ascending, bias last).
// ---------------------------------------------------------------------------
__global__ __launch_bounds__(256) void k_gemm(const float* __restrict__ A,
                                              const float* __restrict__ Wm,
                                              const float* __restrict__ bias,
                                              float* __restrict__ xs,
                                              int row0)
{
    __shared__ float As[16][128];
    __shared__ float Ws[16][128];
    const int t  = threadIdx.x;
    const int bm = blockIdx.x, bn = blockIdx.y;
    const int tx = t & 15, ty = t >> 4;
    const int arow0 = row0 + bm * 128;
    const int wrow0 = bn * 128;

    float accT[8][8];
    float accC[8][8];
#pragma unroll
    for (int i = 0; i < 8; ++i)
#pragma unroll
        for (int j = 0; j < 8; ++j) { accT[i][j] = 0.f; accC[i][j] = 0.f; }

    for (int tile = 0; tile < D_INN / 16; ++tile) {
        const int k0 = tile * 16;
#pragma unroll
        for (int p = 0; p < 2; ++p) {
            const int u = t + p * 256;
            const int r = u >> 2, kq = u & 3;
            const float4 va = *reinterpret_cast<const float4*>(
                &A[(size_t)(arow0 + r) * D_INN + k0 + kq * 4]);
            As[kq * 4 + 0][r] = va.x; As[kq * 4 + 1][r] = va.y;
            As[kq * 4 + 2][r] = va.z; As[kq * 4 + 3][r] = va.w;
            const float4 vw = *reinterpret_cast<const float4*>(
                &Wm[(size_t)(wrow0 + r) * D_INN + k0 + kq * 4]);
            Ws[kq * 4 + 0][r] = vw.x; Ws[kq * 4 + 1][r] = vw.y;
            Ws[kq * 4 + 2][r] = vw.z; Ws[kq * 4 + 3][r] = vw.w;
        }
        __syncthreads();
#pragma unroll
        for (int kk = 0; kk < 16; ++kk) {
            const float4 a0 = *reinterpret_cast<const float4*>(&As[kk][ty * 8]);
            const float4 a1 = *reinterpret_cast<const float4*>(&As[kk][ty * 8 + 4]);
            const float4 w0 = *reinterpret_cast<const float4*>(&Ws[kk][tx * 8]);
            const float4 w1 = *reinterpret_cast<const float4*>(&Ws[kk][tx * 8 + 4]);
            float av[8] = {a0.x, a0.y, a0.z, a0.w, a1.x, a1.y, a1.z, a1.w};
            float wv[8] = {w0.x, w0.y, w0.z, w0.w, w1.x, w1.y, w1.z, w1.w};
#pragma unroll
            for (int i = 0; i < 8; ++i)
#pragma unroll
                for (int j = 0; j < 8; ++j) accC[i][j] += av[i] * wv[j];
        }
        __syncthreads();
        if (((tile + 1) % KC_BLK) == 0) {
#pragma unroll
            for (int i = 0; i < 8; ++i)
#pragma unroll
                for (int j = 0; j < 8; ++j) { accT[i][j] += accC[i][j]; accC[i][j] = 0.f; }
        }
    }
#pragma unroll
    for (int i = 0; i < 8; ++i)
#pragma unroll
        for (int j = 0; j < 8; ++j) accT[i][j] += accC[i][j];

    float bj[8];
#pragma unroll
    for (int j = 0; j < 8; ++j) bj[j] = bias[wrow0 + tx * 8 + j];
#pragma unroll
    for (int i = 0; i < 8; ++i) {
        const int rloc = bm * 128 + ty * 8 + i;
        const size_t base = (size_t)rloc * N_COL + wrow0 + tx * 8;
        float4 o0 = make_float4(accT[i][0] + bj[0], accT[i][1] + bj[1],
                                accT[i][2] + bj[2], accT[i][3] + bj[3]);
        float4 o1 = make_float4(accT[i][4] + bj[4], accT[i][5] + bj[5],
                                accT[i][6] + bj[6], accT[i][7] + bj[7]);
        *reinterpret_cast<float4*>(&xs[base])     = o0;
        *reinterpret_cast<float4*>(&xs[base + 4]) = o1;
    }
}

// ---------------------------------------------------------------------------
// Kernel 2: fast stable-L top-8 per (row, head, half) + tie flag on ranks 0..4.
// Strict-ordered rows: order is unique -> equals np's.  Tied rows: k_exact1
// re-resolves with the exact introsort.
// ---------------------------------------------------------------------------
__device__ inline unsigned long long shfl_xor_u64(unsigned long long v, int m)
{
    unsigned lo = __shfl_xor((unsigned)(v & 0xFFFFFFFFull), m, 64);
    unsigned hi = __shfl_xor((unsigned)(v >> 32), m, 64);
    return ((unsigned long long)hi << 32) | lo;
}

__global__ __launch_bounds__(64) void k_top8(const float* __restrict__ xs,
                                             uint2* __restrict__ cand,
                                             int* __restrict__ flags, int row0)
{
    const int blk  = blockIdx.x;
    const int r    = blk >> 4;
    const int h2   = blk & 15;
    const int lane = threadIdx.x;
    const float* src = xs + (size_t)r * N_COL + h2 * P_BASE;

    float v[16];
#pragma unroll
    for (int w = 0; w < 4; ++w) {
        const float4 f = *reinterpret_cast<const float4*>(&src[(lane + w * 64) * 4]);
        v[w * 4 + 0] = f.x; v[w * 4 + 1] = f.y; v[w * 4 + 2] = f.z; v[w * 4 + 3] = f.w;
    }
    uint2* outp = cand + ((size_t)(row0 + r) * 16 + h2) * 8;

    unsigned long long B[8];
    for (int it = 0; it < 8; ++it) {
        unsigned long long best = 0ull;
#pragma unroll
        for (int q = 0; q < 16; ++q) {
            const int col = lane * 4 + (q >> 2) * 256 + (q & 3);
            unsigned ub = __float_as_uint(v[q]);
            ub = (ub & 0x80000000u) ? ~ub : (ub | 0x80000000u);
            const unsigned long long key =
                ((unsigned long long)ub << 32) | (unsigned)(0xFFFFFFFFu - col);
            if (key > best) best = key;
        }
#pragma unroll
        for (int off = 32; off > 0; off >>= 1) {
            const unsigned long long o = shfl_xor_u64(best, off);
            if (o > best) best = o;
        }
        B[it] = best;
        const int col = (int)(0xFFFFFFFFu - (unsigned)(best & 0xFFFFFFFFull));
        const bool own = (lane == ((col & 255) >> 2));
        const int  qi  = ((col >> 8) << 2) | (col & 3);
#pragma unroll
        for (int q = 0; q < 16; ++q)
            if (own && q == qi) v[q] = -__builtin_inff();
    }

    if (lane == 0) {
        unsigned vb[8];
#pragma unroll
        for (int it = 0; it < 8; ++it) {
            const unsigned tv = (unsigned)(B[it] >> 32);
            vb[it] = (tv & 0x80000000u) ? (tv ^ 0x80000000u) : ~tv;
            const unsigned col = 0xFFFFFFFFu - (unsigned)(B[it] & 0xFFFFFFFFull);
            outp[it] = make_uint2(col, vb[it]);
        }
        int flag = 0;
#pragma unroll
        for (int it = 0; it < 4; ++it)
            if (vb[it] == vb[it + 1]) flag = 1;
        flags[(size_t)(row0 + r) * 16 + h2] = flag;
    }
}

// ---------------------------------------------------------------------------
// Kernel 2b: exact np.argsort(-x)[:4] for flagged (row,half): thread 0 runs
// numpy's introsort (negated comparator) on the 1024 values.
// ---------------------------------------------------------------------------
__global__ __launch_bounds__(64) void k_exact1(const float* __restrict__ xs,
                                               uint2* __restrict__ cand,
                                               const int* __restrict__ flags,
                                               int row0)
{
    __shared__ int tosort[P_BASE];
    const int blk = blockIdx.x;
    const int r   = blk >> 4;
    const int h2  = blk & 15;
    if (!flags[(size_t)(row0 + r) * 16 + h2]) return;

    const float* src = xs + (size_t)r * N_COL + h2 * P_BASE;
    const int t = threadIdx.x;
    for (int i = t; i < P_BASE; i += 64) tosort[i] = i;
    __syncthreads();
    if (t == 0) {
        npy_aqs_desc(src, tosort, P_BASE);
        uint2* outp = cand + ((size_t)(row0 + r) * 16 + h2) * 8;
        for (int s = 0; s < 4; ++s) {
            const int col = tosort[s];               // argsort(-x)[s]
            outp[s] = make_uint2((unsigned)col, __float_as_uint(src[col]));
        }
    }
}

// ---------------------------------------------------------------------------
// Kernel 3: per-(row,head) PKM combine; stage-2 = argsort(-cw)[:4] with n=16
// == stable insertion == ties -> LOWER flat (strict '>' scan).
// ---------------------------------------------------------------------------
__global__ __launch_bounds__(256) void k_combine(const uint2* __restrict__ cand,
                                                 float* __restrict__ wout,
                                                 int* __restrict__ iout)
{
    const int g = blockIdx.x * 256 + threadIdx.x;
    if (g >= B_ROWS * 8) return;
    const int row = g >> 3, head = g & 7;

    const uint2* c1 = &cand[((size_t)row * 16 + head * 2) * 8];
    const uint2* c2 = c1 + 8;
    float w1[4], w2[4]; int i1[4], i2[4];
#pragma unroll
    for (int a = 0; a < 4; ++a) {
        w1[a] = __uint_as_float(c1[a].y); i1[a] = (int)c1[a].x;
        w2[a] = __uint_as_float(c2[a].y); i2[a] = (int)c2[a].x;
    }
    float cw[16];
#pragma unroll
    for (int a = 0; a < 4; ++a)
#pragma unroll
        for (int b2 = 0; b2 < 4; ++b2) {
            const float s  = w1[a] + w2[b2];
            const float rv = (s > 0.0f) ? s : 0.0f;
            const int   ii = i1[a] * P_BASE + i2[b2];
            cw[a * 4 + b2] = (ii >= L_LAT) ? -1.0f : rv;
        }
    bool used[16];
#pragma unroll
    for (int f = 0; f < 16; ++f) used[f] = false;
    for (int j = 0; j < 4; ++j) {
        int bf = -1;
        for (int f = 0; f < 16; ++f) {
            if (used[f]) continue;
            if (bf < 0 || cw[f] > cw[bf]) bf = f;    // ties -> lower flat
        }
        used[bf] = true;
        const int a = bf >> 2, b2 = bf & 3;
        const int ii = i1[a] * P_BASE + i2[b2];
        float wf = cw[bf];
        int ifin;
        if (ii >= L_LAT) { wf = wf * 0.0f; ifin = L_LAT - 1; }  // -1*0 -> -0.0
        else             { ifin = ii; }
        wout[((size_t)row * 8 + head) * 4 + j] = wf;
        iout[((size_t)row * 8 + head) * 4 + j] = ifin;
    }
}

// ---------------------------------------------------------------------------
// Kernel 4: stage-3 = exact np.argsort(-w32) emulation per row.
// ---------------------------------------------------------------------------
__global__ __launch_bounds__(64) void k_final(const float* __restrict__ wout,
                                              const int* __restrict__ iout,
                                              float* __restrict__ out)
{
    const int row = blockIdx.x * 64 + threadIdx.x;
    if (row >= B_ROWS) return;

    float w[32]; int idx[32]; int tosort[32];
    for (int j = 0; j < 32; ++j) {
        w[j]      = wout[(size_t)row * 32 + j];
        idx[j]    = iout[(size_t)row * 32 + j];
        tosort[j] = j;
    }
    npy_aqs_desc(w, tosort, 32);
    for (int j = 0; j < 32; ++j) {
        const int s = tosort[j];                     // argsort(-w)[j]
        out[(size_t)row * 32 + j]                       = w[s];
        out[(size_t)B_ROWS * 32 + (size_t)row * 32 + j] = (float)idx[s];
    }
}

// ---------------------------------------------------------------------------
extern "C" void kernel_launch(void* const* d_in, const int* in_sizes, int n_in,
                              void* d_out, int out_size, void* d_ws, size_t ws_size,
                              hipStream_t stream)
{
    const float* x    = (const float*)d_in[0];
    const float* Wm   = (const float*)d_in[1];
    const float* bias = (const float*)d_in[2];
    float* out = (float*)d_out;

    const size_t candBytes = (size_t)B_ROWS * 16 * 8 * sizeof(uint2);   // 8 MiB
    const size_t flagBytes = (size_t)B_ROWS * 16 * sizeof(int);         // 512 KiB
    const size_t woutBytes = (size_t)B_ROWS * 32 * sizeof(float);       // 1 MiB
    const size_t ioutBytes = (size_t)B_ROWS * 32 * sizeof(int);         // 1 MiB
    const size_t fixedBytes = candBytes + flagBytes + woutBytes + ioutBytes;

    int CH = B_ROWS;
    while (CH > 128 && (size_t)CH * N_COL * sizeof(float) + fixedBytes > ws_size)
        CH >>= 1;

    char*  wsb   = (char*)d_ws;
    float* xs    = (float*)wsb;
    uint2* cand  = (uint2*)(wsb + (size_t)CH * N_COL * sizeof(float));
    int*   flags = (int*)((char*)cand + candBytes);
    float* wout  = (float*)((char*)flags + flagBytes);
    int*   iout  = (int*)((char*)wout + woutBytes);

    for (int row0 = 0; row0 < B_ROWS; row0 += CH) {
        dim3 grid(CH / 128, N_COL / 128);
        k_gemm<<<grid, 256, 0, stream>>>(x, Wm, bias, xs, row0);
        k_top8<<<CH * 16, 64, 0, stream>>>(xs, cand, flags, row0);
        k_exact1<<<CH * 16, 64, 0, stream>>>(xs, cand, flags, row0);
    }
    k_combine<<<(B_ROWS * 8 + 255) / 256, 256, 0, stream>>>(cand, wout, iout);
    k_final<<<(B_ROWS + 63) / 64, 64, 0, stream>>>(wout, iout, out);
}

// Round 15
// 5974.330 us; speedup vs baseline: 1.8612x; 1.8612x over previous
//
#include <hip/hip_runtime.h>

#define B_ROWS 8192
#define D_INN  2048
#define N_COL  16384
#define P_BASE 1024
#define L_LAT  600000

typedef unsigned short ushort_t;
typedef __attribute__((ext_vector_type(8))) __bf16 bf16x8;
typedef __attribute__((ext_vector_type(4))) float  f32x4;

// ---------------------------------------------------------------------------
// numpy aquicksort (introsort, argsort variant) with LT(a,b) := (b<a):
// exactly np.argsort(-x): descending with numpy's unstable tie behavior.
// ---------------------------------------------------------------------------
#define NPY_LT(a, b) ((b) < (a))
__device__ void npy_aqs_desc(const float* __restrict__ v, int* tosort, int n)
{
    const int SMALL = 15;
    int stack[64]; int sp = 0;
    int pl = 0, pr = n - 1;
    for (;;) {
        while (pr - pl > SMALL) {
            const int pm = pl + ((pr - pl) >> 1);
            if (NPY_LT(v[tosort[pm]], v[tosort[pl]])) { int t = tosort[pm]; tosort[pm] = tosort[pl]; tosort[pl] = t; }
            if (NPY_LT(v[tosort[pr]], v[tosort[pm]])) { int t = tosort[pr]; tosort[pr] = tosort[pm]; tosort[pm] = t; }
            if (NPY_LT(v[tosort[pm]], v[tosort[pl]])) { int t = tosort[pm]; tosort[pm] = tosort[pl]; tosort[pl] = t; }
            const float vp = v[tosort[pm]];
            int pi = pl;
            int pj = pr - 1;
            { int t = tosort[pm]; tosort[pm] = tosort[pj]; tosort[pj] = t; }
            for (;;) {
                do { ++pi; } while (NPY_LT(v[tosort[pi]], vp));
                do { --pj; } while (NPY_LT(vp, v[tosort[pj]]));
                if (pi >= pj) break;
                int t = tosort[pi]; tosort[pi] = tosort[pj]; tosort[pj] = t;
            }
            const int pk = pr - 1;
            { int t = tosort[pi]; tosort[pi] = tosort[pk]; tosort[pk] = t; }
            if (pi - pl < pr - pi) { stack[sp++] = pi + 1; stack[sp++] = pr;     pr = pi - 1; }
            else                   { stack[sp++] = pl;     stack[sp++] = pi - 1; pl = pi + 1; }
        }
        for (int i = pl + 1; i <= pr; ++i) {
            const int vi = tosort[i];
            const float vp = v[vi];
            int j = i;
            while (j > pl && NPY_LT(vp, v[tosort[j - 1]])) { tosort[j] = tosort[j - 1]; --j; }
            tosort[j] = vi;
        }
        if (sp == 0) break;
        pr = stack[--sp]; pl = stack[--sp];
    }
}

// ---------------------------------------------------------------------------
// Kernel 0: f32 -> bf16 (RNE) copies of x and W.
// ---------------------------------------------------------------------------
__device__ inline unsigned f2b_rne(float f)
{
    const unsigned u = __float_as_uint(f);
    return (u + 0x7FFFu + ((u >> 16) & 1u)) >> 16;
}

__global__ __launch_bounds__(256) void k_prep(const float* __restrict__ x,
                                              const float* __restrict__ Wm,
                                              ushort_t* __restrict__ xb,
                                              ushort_t* __restrict__ wb)
{
    const size_t n1 = (size_t)B_ROWS * D_INN / 4;     // float4 count for x
    const size_t n2 = (size_t)N_COL * D_INN / 4;      // float4 count for W
    const size_t stride = (size_t)gridDim.x * blockDim.x;
    for (size_t i = (size_t)blockIdx.x * blockDim.x + threadIdx.x; i < n1 + n2; i += stride) {
        const float4 f = (i < n1) ? reinterpret_cast<const float4*>(x)[i]
                                  : reinterpret_cast<const float4*>(Wm)[i - n1];
        uint2 o;
        o.x = f2b_rne(f.x) | (f2b_rne(f.y) << 16);
        o.y = f2b_rne(f.z) | (f2b_rne(f.w) << 16);
        if (i < n1) reinterpret_cast<uint2*>(xb)[i]      = o;
        else        reinterpret_cast<uint2*>(wb)[i - n1] = o;
    }
}

// ---------------------------------------------------------------------------
// Kernel 1: bf16 MFMA GEMM  xs_approx = xb @ wb^T + b  (shortlist only).
// 128x128 tile, BK=32, 4 waves (2x2), 16x16x32 MFMA, 4x4 frags/wave.
// ---------------------------------------------------------------------------
__global__ __launch_bounds__(256) void k_mfma(const ushort_t* __restrict__ xb,
                                              const ushort_t* __restrict__ wb,
                                              const float* __restrict__ bias,
                                              float* __restrict__ xs, int row0)
{
    __shared__ ushort_t As[128][32];
    __shared__ ushort_t Bs[128][32];
    const int t = threadIdx.x;
    const int bm = blockIdx.x, bn = blockIdx.y;
    const int wid = t >> 6, lane = t & 63;
    const int wm = wid >> 1, wn = wid & 1;
    const int arow0 = row0 + bm * 128;
    const int wrow0 = bn * 128;
    const int l15 = lane & 15, lg = lane >> 4;

    f32x4 acc[4][4];
#pragma unroll
    for (int i = 0; i < 4; ++i)
#pragma unroll
        for (int j = 0; j < 4; ++j) acc[i][j] = (f32x4){0.f, 0.f, 0.f, 0.f};

    for (int k0 = 0; k0 < D_INN; k0 += 32) {
#pragma unroll
        for (int p = 0; p < 2; ++p) {
            const int u = t + p * 256;
            const int r = u >> 2, g = u & 3;
            *reinterpret_cast<uint4*>(&As[r][g * 8]) =
                *reinterpret_cast<const uint4*>(&xb[(size_t)(arow0 + r) * D_INN + k0 + g * 8]);
            *reinterpret_cast<uint4*>(&Bs[r][g * 8]) =
                *reinterpret_cast<const uint4*>(&wb[(size_t)(wrow0 + r) * D_INN + k0 + g * 8]);
        }
        __syncthreads();
        bf16x8 af[4], bg[4];
#pragma unroll
        for (int i = 0; i < 4; ++i)
            af[i] = __builtin_bit_cast(bf16x8,
                *reinterpret_cast<const uint4*>(&As[wm * 64 + i * 16 + l15][lg * 8]));
#pragma unroll
        for (int j = 0; j < 4; ++j)
            bg[j] = __builtin_bit_cast(bf16x8,
                *reinterpret_cast<const uint4*>(&Bs[wn * 64 + j * 16 + l15][lg * 8]));
#pragma unroll
        for (int i = 0; i < 4; ++i)
#pragma unroll
            for (int j = 0; j < 4; ++j)
                acc[i][j] = __builtin_amdgcn_mfma_f32_16x16x32_bf16(af[i], bg[j], acc[i][j], 0, 0, 0);
        __syncthreads();
    }

#pragma unroll
    for (int i = 0; i < 4; ++i)
#pragma unroll
        for (int j = 0; j < 4; ++j) {
            const int col = wn * 64 + j * 16 + l15;
            const float bj = bias[wrow0 + col];
#pragma unroll
            for (int q = 0; q < 4; ++q) {
                const int rloc = bm * 128 + wm * 64 + i * 16 + lg * 4 + q;
                xs[(size_t)rloc * N_COL + wrow0 + col] = acc[i][j][q] + bj;
            }
        }
}

// ---------------------------------------------------------------------------
// Kernel 2: approx top-8 per (row, head, half).  Shortlist columns only.
// ---------------------------------------------------------------------------
__device__ inline unsigned long long shfl_xor_u64(unsigned long long v, int m)
{
    unsigned lo = __shfl_xor((unsigned)(v & 0xFFFFFFFFull), m, 64);
    unsigned hi = __shfl_xor((unsigned)(v >> 32), m, 64);
    return ((unsigned long long)hi << 32) | lo;
}

__global__ __launch_bounds__(64) void k_top8(const float* __restrict__ xs,
                                             uint2* __restrict__ cand, int row0)
{
    const int blk  = blockIdx.x;
    const int r    = blk >> 4;
    const int h2   = blk & 15;
    const int lane = threadIdx.x;
    const float* src = xs + (size_t)r * N_COL + h2 * P_BASE;

    float v[16];
#pragma unroll
    for (int w = 0; w < 4; ++w) {
        const float4 f = *reinterpret_cast<const float4*>(&src[(lane + w * 64) * 4]);
        v[w * 4 + 0] = f.x; v[w * 4 + 1] = f.y; v[w * 4 + 2] = f.z; v[w * 4 + 3] = f.w;
    }
    uint2* outp = cand + ((size_t)(row0 + r) * 16 + h2) * 8;

    for (int it = 0; it < 8; ++it) {
        unsigned long long best = 0ull;
#pragma unroll
        for (int q = 0; q < 16; ++q) {
            const int col = lane * 4 + (q >> 2) * 256 + (q & 3);
            unsigned ub = __float_as_uint(v[q]);
            ub = (ub & 0x80000000u) ? ~ub : (ub | 0x80000000u);
            const unsigned long long key =
                ((unsigned long long)ub << 32) | (unsigned)(0xFFFFFFFFu - col);
            if (key > best) best = key;
        }
#pragma unroll
        for (int off = 32; off > 0; off >>= 1) {
            const unsigned long long o = shfl_xor_u64(best, off);
            if (o > best) best = o;
        }
        const int col = (int)(0xFFFFFFFFu - (unsigned)(best & 0xFFFFFFFFull));
        if (lane == 0) outp[it] = make_uint2((unsigned)col, 0u);
        const bool own = (lane == ((col & 255) >> 2));
        const int  qi  = ((col >> 8) << 2) | (col & 3);
#pragma unroll
        for (int q = 0; q < 16; ++q)
            if (own && q == qi) v[q] = -__builtin_inff();
    }
}

// ---------------------------------------------------------------------------
// Kernel 3: exact kc=288 recompute of the 8 shortlisted dots per (row, half),
// exact stable-L sort, write exact (col, valbits), flag bit-ties ranks 0..4.
// Chain bit-identical to r14's k_gemm: sequential FMA within 288-panels,
// panels folded ascending, tail, then +bias.
// ---------------------------------------------------------------------------
__global__ __launch_bounds__(128) void k_refine(const float* __restrict__ x,
                                                const float* __restrict__ Wm,
                                                const float* __restrict__ bias,
                                                uint2* __restrict__ cand,
                                                int* __restrict__ flags)
{
    __shared__ float xrow[D_INN];
    __shared__ float sval[128];
    const int row = blockIdx.x;
    const int t   = threadIdx.x;

#pragma unroll
    for (int p = 0; p < 4; ++p)
        *reinterpret_cast<float4*>(&xrow[(t + p * 128) * 4]) =
            *reinterpret_cast<const float4*>(&x[(size_t)row * D_INN + (t + p * 128) * 4]);
    __syncthreads();

    const int h2 = t >> 3, c = t & 7;
    const int col  = (int)cand[((size_t)row * 16 + h2) * 8 + c].x;
    const int wcol = (h2 >> 1) * 2048 + (h2 & 1) * P_BASE + col;
    const float* wr = &Wm[(size_t)wcol * D_INN];

    float accT = 0.f, accC = 0.f;
    int j = 0;
    for (int p = 0; p < 7; ++p) {          // 7 panels of 288
#pragma unroll 8
        for (int q = 0; q < 288; ++q, ++j) accC = fmaf(xrow[j], wr[j], accC);
        accT += accC; accC = 0.f;
    }
#pragma unroll 8
    for (; j < D_INN; ++j) accC = fmaf(xrow[j], wr[j], accC);   // 32 tail
    accT += accC;
    sval[t] = accT + bias[wcol];
    __syncthreads();

    if (t < 16) {
        float v[8]; int cl[8];
        for (int s = 0; s < 8; ++s) {
            v[s]  = sval[t * 8 + s];
            cl[s] = (int)cand[((size_t)row * 16 + t) * 8 + s].x;
        }
        for (int a = 0; a < 8; ++a) {       // desc, ties -> lower col
            int b = a;
            for (int q = a + 1; q < 8; ++q)
                if (v[q] > v[b] || (v[q] == v[b] && cl[q] < cl[b])) b = q;
            float tv = v[a]; v[a] = v[b]; v[b] = tv;
            int   tc = cl[a]; cl[a] = cl[b]; cl[b] = tc;
        }
        uint2* outp = &cand[((size_t)row * 16 + t) * 8];
        int flag = 0;
        for (int s = 0; s < 8; ++s) outp[s] = make_uint2((unsigned)cl[s], __float_as_uint(v[s]));
        for (int s = 0; s < 4; ++s)
            if (__float_as_uint(v[s]) == __float_as_uint(v[s + 1])) flag = 1;
        flags[(size_t)row * 16 + t] = flag;
    }
}

// ---------------------------------------------------------------------------
// Kernel 3b: flagged halves -> exact 1024 dots + numpy introsort; write top-4.
// ---------------------------------------------------------------------------
__global__ __launch_bounds__(256) void k_exact1024(const float* __restrict__ x,
                                                   const float* __restrict__ Wm,
                                                   const float* __restrict__ bias,
                                                   uint2* __restrict__ cand,
                                                   const int* __restrict__ flags)
{
    const int rh = blockIdx.x;
    if (!flags[rh]) return;
    __shared__ float xrow[D_INN];
    __shared__ float v[P_BASE];
    __shared__ int   tosort[P_BASE];
    const int row = rh >> 4, h2 = rh & 15;
    const int t = threadIdx.x;

#pragma unroll
    for (int p = 0; p < 2; ++p)
        *reinterpret_cast<float4*>(&xrow[(t + p * 256) * 4]) =
            *reinterpret_cast<const float4*>(&x[(size_t)row * D_INN + (t + p * 256) * 4]);
    __syncthreads();

    const int wbase = (h2 >> 1) * 2048 + (h2 & 1) * P_BASE;
    for (int cc = 0; cc < 4; ++cc) {
        const int col = t + cc * 256;
        const float* wr = &Wm[(size_t)(wbase + col) * D_INN];
        float accT = 0.f, accC = 0.f;
        int j = 0;
        for (int p = 0; p < 7; ++p) {
            for (int q = 0; q < 288; ++q, ++j) accC = fmaf(xrow[j], wr[j], accC);
            accT += accC; accC = 0.f;
        }
        for (; j < D_INN; ++j) accC = fmaf(xrow[j], wr[j], accC);
        accT += accC;
        v[col] = accT + bias[wbase + col];
        tosort[col] = col;
    }
    __syncthreads();
    if (t == 0) {
        npy_aqs_desc(v, tosort, P_BASE);
        uint2* outp = &cand[(size_t)rh * 8];
        for (int s = 0; s < 4; ++s) {
            const int c2 = tosort[s];
            outp[s] = make_uint2((unsigned)c2, __float_as_uint(v[c2]));
        }
    }
}

// ---------------------------------------------------------------------------
// Kernel 4: per-(row,head) PKM combine (verbatim r14: stage-2 stable-L).
// ---------------------------------------------------------------------------
__global__ __launch_bounds__(256) void k_combine(const uint2* __restrict__ cand,
                                                 float* __restrict__ wout,
                                                 int* __restrict__ iout)
{
    const int g = blockIdx.x * 256 + threadIdx.x;
    if (g >= B_ROWS * 8) return;
    const int row = g >> 3, head = g & 7;

    const uint2* c1 = &cand[((size_t)row * 16 + head * 2) * 8];
    const uint2* c2 = c1 + 8;
    float w1[4], w2[4]; int i1[4], i2[4];
#pragma unroll
    for (int a = 0; a < 4; ++a) {
        w1[a] = __uint_as_float(c1[a].y); i1[a] = (int)c1[a].x;
        w2[a] = __uint_as_float(c2[a].y); i2[a] = (int)c2[a].x;
    }
    float cw[16];
#pragma unroll
    for (int a = 0; a < 4; ++a)
#pragma unroll
        for (int b2 = 0; b2 < 4; ++b2) {
            const float s  = w1[a] + w2[b2];
            const float rv = (s > 0.0f) ? s : 0.0f;
            const int   ii = i1[a] * P_BASE + i2[b2];
            cw[a * 4 + b2] = (ii >= L_LAT) ? -1.0f : rv;
        }
    bool used[16];
#pragma unroll
    for (int f = 0; f < 16; ++f) used[f] = false;
    for (int j = 0; j < 4; ++j) {
        int bf = -1;
        for (int f = 0; f < 16; ++f) {
            if (used[f]) continue;
            if (bf < 0 || cw[f] > cw[bf]) bf = f;    // ties -> lower flat
        }
        used[bf] = true;
        const int a = bf >> 2, b2 = bf & 3;
        const int ii = i1[a] * P_BASE + i2[b2];
        float wf = cw[bf];
        int ifin;
        if (ii >= L_LAT) { wf = wf * 0.0f; ifin = L_LAT - 1; }
        else             { ifin = ii; }
        wout[((size_t)row * 8 + head) * 4 + j] = wf;
        iout[((size_t)row * 8 + head) * 4 + j] = ifin;
    }
}

// ---------------------------------------------------------------------------
// Kernel 5: stage-3 exact np.argsort(-w32) per row (verbatim r14).
// ---------------------------------------------------------------------------
__global__ __launch_bounds__(64) void k_final(const float* __restrict__ wout,
                                              const int* __restrict__ iout,
                                              float* __restrict__ out)
{
    const int row = blockIdx.x * 64 + threadIdx.x;
    if (row >= B_ROWS) return;

    float w[32]; int idx[32]; int tosort[32];
    for (int j = 0; j < 32; ++j) {
        w[j]      = wout[(size_t)row * 32 + j];
        idx[j]    = iout[(size_t)row * 32 + j];
        tosort[j] = j;
    }
    npy_aqs_desc(w, tosort, 32);
    for (int j = 0; j < 32; ++j) {
        const int s = tosort[j];
        out[(size_t)row * 32 + j]                       = w[s];
        out[(size_t)B_ROWS * 32 + (size_t)row * 32 + j] = (float)idx[s];
    }
}

// ---------------------------------------------------------------------------
extern "C" void kernel_launch(void* const* d_in, const int* in_sizes, int n_in,
                              void* d_out, int out_size, void* d_ws, size_t ws_size,
                              hipStream_t stream)
{
    const float* x    = (const float*)d_in[0];
    const float* Wm   = (const float*)d_in[1];
    const float* bias = (const float*)d_in[2];
    float* out = (float*)d_out;

    const size_t xbBytes   = (size_t)B_ROWS * D_INN * 2;                // 32 MiB
    const size_t wbBytes   = (size_t)N_COL * D_INN * 2;                 // 64 MiB
    const size_t candBytes = (size_t)B_ROWS * 16 * 8 * sizeof(uint2);   // 8 MiB
    const size_t flagBytes = (size_t)B_ROWS * 16 * sizeof(int);         // 512 KiB
    const size_t woutBytes = (size_t)B_ROWS * 32 * sizeof(float);       // 1 MiB
    const size_t ioutBytes = (size_t)B_ROWS * 32 * sizeof(int);         // 1 MiB
    const size_t fixedBytes = xbBytes + wbBytes + candBytes + flagBytes + woutBytes + ioutBytes;

    int CH = B_ROWS;
    while (CH > 128 && (size_t)CH * N_COL * sizeof(float) + fixedBytes > ws_size)
        CH >>= 1;

    char*     wsb   = (char*)d_ws;
    float*    xs    = (float*)wsb;
    ushort_t* xb    = (ushort_t*)(wsb + (size_t)CH * N_COL * sizeof(float));
    ushort_t* wb    = (ushort_t*)((char*)xb + xbBytes);
    uint2*    cand  = (uint2*)((char*)wb + wbBytes);
    int*      flags = (int*)((char*)cand + candBytes);
    float*    wout  = (float*)((char*)flags + flagBytes);
    int*      iout  = (int*)((char*)wout + woutBytes);

    k_prep<<<1024, 256, 0, stream>>>(x, Wm, xb, wb);

    for (int row0 = 0; row0 < B_ROWS; row0 += CH) {
        dim3 grid(CH / 128, N_COL / 128);
        k_mfma<<<grid, 256, 0, stream>>>(xb, wb, bias, xs, row0);
        k_top8<<<CH * 16, 64, 0, stream>>>(xs, cand, row0);
    }
    k_refine<<<B_ROWS, 128, 0, stream>>>(x, Wm, bias, cand, flags);
    k_exact1024<<<B_ROWS * 16, 256, 0, stream>>>(x, Wm, bias, cand, flags);
    k_combine<<<(B_ROWS * 8 + 255) / 256, 256, 0, stream>>>(cand, wout, iout);
    k_final<<<(B_ROWS + 63) / 64, 64, 0, stream>>>(wout, iout, out);
}

// Round 16
// 4317.089 us; speedup vs baseline: 2.5757x; 1.3839x over previous
//
#include <hip/hip_runtime.h>

#define B_ROWS 8192
#define D_INN  2048
#define N_COL  16384
#define P_BASE 1024
#define L_LAT  600000

typedef unsigned short ushort_t;
typedef __attribute__((ext_vector_type(8))) __bf16 bf16x8;
typedef __attribute__((ext_vector_type(4))) float  f32x4;

// ---------------------------------------------------------------------------
// numpy aquicksort (introsort, argsort variant) with LT(a,b) := (b<a):
// exactly np.argsort(-x): descending with numpy's unstable tie behavior.
// ---------------------------------------------------------------------------
#define NPY_LT(a, b) ((b) < (a))
__device__ void npy_aqs_desc(const float* __restrict__ v, int* tosort, int n)
{
    const int SMALL = 15;
    int stack[64]; int sp = 0;
    int pl = 0, pr = n - 1;
    for (;;) {
        while (pr - pl > SMALL) {
            const int pm = pl + ((pr - pl) >> 1);
            if (NPY_LT(v[tosort[pm]], v[tosort[pl]])) { int t = tosort[pm]; tosort[pm] = tosort[pl]; tosort[pl] = t; }
            if (NPY_LT(v[tosort[pr]], v[tosort[pm]])) { int t = tosort[pr]; tosort[pr] = tosort[pm]; tosort[pm] = t; }
            if (NPY_LT(v[tosort[pm]], v[tosort[pl]])) { int t = tosort[pm]; tosort[pm] = tosort[pl]; tosort[pl] = t; }
            const float vp = v[tosort[pm]];
            int pi = pl;
            int pj = pr - 1;
            { int t = tosort[pm]; tosort[pm] = tosort[pj]; tosort[pj] = t; }
            for (;;) {
                do { ++pi; } while (NPY_LT(v[tosort[pi]], vp));
                do { --pj; } while (NPY_LT(vp, v[tosort[pj]]));
                if (pi >= pj) break;
                int t = tosort[pi]; tosort[pi] = tosort[pj]; tosort[pj] = t;
            }
            const int pk = pr - 1;
            { int t = tosort[pi]; tosort[pi] = tosort[pk]; tosort[pk] = t; }
            if (pi - pl < pr - pi) { stack[sp++] = pi + 1; stack[sp++] = pr;     pr = pi - 1; }
            else                   { stack[sp++] = pl;     stack[sp++] = pi - 1; pl = pi + 1; }
        }
        for (int i = pl + 1; i <= pr; ++i) {
            const int vi = tosort[i];
            const float vp = v[vi];
            int j = i;
            while (j > pl && NPY_LT(vp, v[tosort[j - 1]])) { tosort[j] = tosort[j - 1]; --j; }
            tosort[j] = vi;
        }
        if (sp == 0) break;
        pr = stack[--sp]; pl = stack[--sp];
    }
}

// ---------------------------------------------------------------------------
// Kernel 0: f32 -> bf16 (RNE) copies of x and W.
// ---------------------------------------------------------------------------
__device__ inline unsigned f2b_rne(float f)
{
    const unsigned u = __float_as_uint(f);
    return (u + 0x7FFFu + ((u >> 16) & 1u)) >> 16;
}

__global__ __launch_bounds__(256) void k_prep(const float* __restrict__ x,
                                              const float* __restrict__ Wm,
                                              ushort_t* __restrict__ xb,
                                              ushort_t* __restrict__ wb)
{
    const size_t n1 = (size_t)B_ROWS * D_INN / 4;
    const size_t n2 = (size_t)N_COL * D_INN / 4;
    const size_t stride = (size_t)gridDim.x * blockDim.x;
    for (size_t i = (size_t)blockIdx.x * blockDim.x + threadIdx.x; i < n1 + n2; i += stride) {
        const float4 f = (i < n1) ? reinterpret_cast<const float4*>(x)[i]
                                  : reinterpret_cast<const float4*>(Wm)[i - n1];
        uint2 o;
        o.x = f2b_rne(f.x) | (f2b_rne(f.y) << 16);
        o.y = f2b_rne(f.z) | (f2b_rne(f.w) << 16);
        if (i < n1) reinterpret_cast<uint2*>(xb)[i]      = o;
        else        reinterpret_cast<uint2*>(wb)[i - n1] = o;
    }
}

// ---------------------------------------------------------------------------
// Kernel 1: bf16 MFMA GEMM (shortlist).  128x128 tile, BK=32, 4 waves (2x2),
// staging via global_load_lds width=16 (linear LDS dest == [128][32] layout).
// ---------------------------------------------------------------------------
__global__ __launch_bounds__(256) void k_mfma(const ushort_t* __restrict__ xb,
                                              const ushort_t* __restrict__ wb,
                                              const float* __restrict__ bias,
                                              float* __restrict__ xs, int row0)
{
    __shared__ ushort_t As[128][32];
    __shared__ ushort_t Bs[128][32];
    const int t = threadIdx.x;
    const int bm = blockIdx.x, bn = blockIdx.y;
    const int wid = t >> 6, lane = t & 63;
    const int wm = wid >> 1, wn = wid & 1;
    const int arow0 = row0 + bm * 128;
    const int wrow0 = bn * 128;
    const int l15 = lane & 15, lg = lane >> 4;
    const int sr = lane >> 2;              // staging row within 16-row chunk
    const int sc = (lane & 3) * 16;        // staging byte offset in 64B slab

    f32x4 acc[4][4];
#pragma unroll
    for (int i = 0; i < 4; ++i)
#pragma unroll
        for (int j = 0; j < 4; ++j) acc[i][j] = (f32x4){0.f, 0.f, 0.f, 0.f};

    for (int k0 = 0; k0 < D_INN; k0 += 32) {
#pragma unroll
        for (int e = 0; e < 2; ++e) {
            const int c = wid * 2 + e;     // 8 chunks of 16 rows
            const char* ga = (const char*)xb +
                (((size_t)(arow0 + c * 16 + sr)) * D_INN + k0) * 2 + sc;
            const char* gb = (const char*)wb +
                (((size_t)(wrow0 + c * 16 + sr)) * D_INN + k0) * 2 + sc;
            __builtin_amdgcn_global_load_lds(
                (const __attribute__((address_space(1))) void*)ga,
                (__attribute__((address_space(3))) void*)((char*)&As[0][0] + c * 1024),
                16, 0, 0);
            __builtin_amdgcn_global_load_lds(
                (const __attribute__((address_space(1))) void*)gb,
                (__attribute__((address_space(3))) void*)((char*)&Bs[0][0] + c * 1024),
                16, 0, 0);
        }
        __syncthreads();
        bf16x8 af[4], bg[4];
#pragma unroll
        for (int i = 0; i < 4; ++i)
            af[i] = __builtin_bit_cast(bf16x8,
                *reinterpret_cast<const uint4*>(&As[wm * 64 + i * 16 + l15][lg * 8]));
#pragma unroll
        for (int j = 0; j < 4; ++j)
            bg[j] = __builtin_bit_cast(bf16x8,
                *reinterpret_cast<const uint4*>(&Bs[wn * 64 + j * 16 + l15][lg * 8]));
#pragma unroll
        for (int i = 0; i < 4; ++i)
#pragma unroll
            for (int j = 0; j < 4; ++j)
                acc[i][j] = __builtin_amdgcn_mfma_f32_16x16x32_bf16(af[i], bg[j], acc[i][j], 0, 0, 0);
        __syncthreads();
    }

#pragma unroll
    for (int i = 0; i < 4; ++i)
#pragma unroll
        for (int j = 0; j < 4; ++j) {
            const int col = wn * 64 + j * 16 + l15;
            const float bj = bias[wrow0 + col];
#pragma unroll
            for (int q = 0; q < 4; ++q) {
                const int rloc = bm * 128 + wm * 64 + i * 16 + lg * 4 + q;
                xs[(size_t)rloc * N_COL + wrow0 + col] = acc[i][j][q] + bj;
            }
        }
}

// ---------------------------------------------------------------------------
// Kernel 2: approx top-6 per (row, head, half).  Shortlist columns only.
// ---------------------------------------------------------------------------
__device__ inline unsigned long long shfl_xor_u64(unsigned long long v, int m)
{
    unsigned lo = __shfl_xor((unsigned)(v & 0xFFFFFFFFull), m, 64);
    unsigned hi = __shfl_xor((unsigned)(v >> 32), m, 64);
    return ((unsigned long long)hi << 32) | lo;
}

__global__ __launch_bounds__(64) void k_top8(const float* __restrict__ xs,
                                             uint2* __restrict__ cand, int row0)
{
    const int blk  = blockIdx.x;
    const int r    = blk >> 4;
    const int h2   = blk & 15;
    const int lane = threadIdx.x;
    const float* src = xs + (size_t)r * N_COL + h2 * P_BASE;

    float v[16];
#pragma unroll
    for (int w = 0; w < 4; ++w) {
        const float4 f = *reinterpret_cast<const float4*>(&src[(lane + w * 64) * 4]);
        v[w * 4 + 0] = f.x; v[w * 4 + 1] = f.y; v[w * 4 + 2] = f.z; v[w * 4 + 3] = f.w;
    }
    uint2* outp = cand + ((size_t)(row0 + r) * 16 + h2) * 8;

    for (int it = 0; it < 6; ++it) {
        unsigned long long best = 0ull;
#pragma unroll
        for (int q = 0; q < 16; ++q) {
            const int col = lane * 4 + (q >> 2) * 256 + (q & 3);
            unsigned ub = __float_as_uint(v[q]);
            ub = (ub & 0x80000000u) ? ~ub : (ub | 0x80000000u);
            const unsigned long long key =
                ((unsigned long long)ub << 32) | (unsigned)(0xFFFFFFFFu - col);
            if (key > best) best = key;
        }
#pragma unroll
        for (int off = 32; off > 0; off >>= 1) {
            const unsigned long long o = shfl_xor_u64(best, off);
            if (o > best) best = o;
        }
        const int col = (int)(0xFFFFFFFFu - (unsigned)(best & 0xFFFFFFFFull));
        if (lane == 0) outp[it] = make_uint2((unsigned)col, 0u);
        const bool own = (lane == ((col & 255) >> 2));
        const int  qi  = ((col >> 8) << 2) | (col & 3);
#pragma unroll
        for (int q = 0; q < 16; ++q)
            if (own && q == qi) v[q] = -__builtin_inff();
    }
}

// ---------------------------------------------------------------------------
// Kernel 3: exact kc=288 recompute of the 6 shortlisted dots per (row, half),
// float4 loads, bit-identical sequential FMA chain; exact stable-L sort of 6;
// write slots 0..5; flag bit-ties among ranks 0..4.
// ---------------------------------------------------------------------------
__global__ __launch_bounds__(128) void k_refine(const float* __restrict__ x,
                                                const float* __restrict__ Wm,
                                                const float* __restrict__ bias,
                                                uint2* __restrict__ cand,
                                                int* __restrict__ flags)
{
    __shared__ float xrow[D_INN];
    __shared__ float sval[96];
    const int row = blockIdx.x;
    const int t   = threadIdx.x;

#pragma unroll
    for (int p = 0; p < 4; ++p)
        *reinterpret_cast<float4*>(&xrow[(t + p * 128) * 4]) =
            *reinterpret_cast<const float4*>(&x[(size_t)row * D_INN + (t + p * 128) * 4]);
    __syncthreads();

    if (t < 96) {
        const int h2 = t / 6, c = t % 6;
        const int col  = (int)cand[((size_t)row * 16 + h2) * 8 + c].x;
        const int wcol = (h2 >> 1) * 2048 + (h2 & 1) * P_BASE + col;
        const float4* wr4 = reinterpret_cast<const float4*>(&Wm[(size_t)wcol * D_INN]);
        const float4* xr4 = reinterpret_cast<const float4*>(xrow);

        float accT = 0.f, accC = 0.f;
        int j4 = 0;
        for (int p = 0; p < 7; ++p) {          // 7 panels of 288 (= 72 float4)
#pragma unroll 4
            for (int q = 0; q < 72; ++q, ++j4) {
                const float4 w4 = wr4[j4];
                const float4 x4 = xr4[j4];
                accC = fmaf(x4.x, w4.x, accC);
                accC = fmaf(x4.y, w4.y, accC);
                accC = fmaf(x4.z, w4.z, accC);
                accC = fmaf(x4.w, w4.w, accC);
            }
            accT += accC; accC = 0.f;
        }
#pragma unroll
        for (int q = 0; q < 8; ++q, ++j4) {    // 32-tail (= 8 float4)
            const float4 w4 = wr4[j4];
            const float4 x4 = xr4[j4];
            accC = fmaf(x4.x, w4.x, accC);
            accC = fmaf(x4.y, w4.y, accC);
            accC = fmaf(x4.z, w4.z, accC);
            accC = fmaf(x4.w, w4.w, accC);
        }
        accT += accC;
        sval[t] = accT + bias[wcol];
    }
    __syncthreads();

    if (t < 16) {
        float v[6]; int cl[6];
        for (int s = 0; s < 6; ++s) {
            v[s]  = sval[t * 6 + s];
            cl[s] = (int)cand[((size_t)row * 16 + t) * 8 + s].x;
        }
        for (int a = 0; a < 6; ++a) {          // desc, ties -> lower col
            int b = a;
            for (int q = a + 1; q < 6; ++q)
                if (v[q] > v[b] || (v[q] == v[b] && cl[q] < cl[b])) b = q;
            float tv = v[a]; v[a] = v[b]; v[b] = tv;
            int   tc = cl[a]; cl[a] = cl[b]; cl[b] = tc;
        }
        uint2* outp = &cand[((size_t)row * 16 + t) * 8];
        int flag = 0;
        for (int s = 0; s < 6; ++s) outp[s] = make_uint2((unsigned)cl[s], __float_as_uint(v[s]));
        for (int s = 0; s < 4; ++s)
            if (__float_as_uint(v[s]) == __float_as_uint(v[s + 1])) flag = 1;
        flags[(size_t)row * 16 + t] = flag;
    }
}

// ---------------------------------------------------------------------------
// Kernel 3b: flagged halves -> exact 1024 dots + numpy introsort; write top-4.
// ---------------------------------------------------------------------------
__global__ __launch_bounds__(256) void k_exact1024(const float* __restrict__ x,
                                                   const float* __restrict__ Wm,
                                                   const float* __restrict__ bias,
                                                   uint2* __restrict__ cand,
                                                   const int* __restrict__ flags)
{
    const int rh = blockIdx.x;
    if (!flags[rh]) return;
    __shared__ float xrow[D_INN];
    __shared__ float v[P_BASE];
    __shared__ int   tosort[P_BASE];
    const int row = rh >> 4, h2 = rh & 15;
    const int t = threadIdx.x;

#pragma unroll
    for (int p = 0; p < 2; ++p)
        *reinterpret_cast<float4*>(&xrow[(t + p * 256) * 4]) =
            *reinterpret_cast<const float4*>(&x[(size_t)row * D_INN + (t + p * 256) * 4]);
    __syncthreads();

    const int wbase = (h2 >> 1) * 2048 + (h2 & 1) * P_BASE;
    for (int cc = 0; cc < 4; ++cc) {
        const int col = t + cc * 256;
        const float* wr = &Wm[(size_t)(wbase + col) * D_INN];
        float accT = 0.f, accC = 0.f;
        int j = 0;
        for (int p = 0; p < 7; ++p) {
            for (int q = 0; q < 288; ++q, ++j) accC = fmaf(xrow[j], wr[j], accC);
            accT += accC; accC = 0.f;
        }
        for (; j < D_INN; ++j) accC = fmaf(xrow[j], wr[j], accC);
        accT += accC;
        v[col] = accT + bias[wbase + col];
        tosort[col] = col;
    }
    __syncthreads();
    if (t == 0) {
        npy_aqs_desc(v, tosort, P_BASE);
        uint2* outp = &cand[(size_t)rh * 8];
        for (int s = 0; s < 4; ++s) {
            const int c2 = tosort[s];
            outp[s] = make_uint2((unsigned)c2, __float_as_uint(v[c2]));
        }
    }
}

// ---------------------------------------------------------------------------
// Kernel 4: per-(row,head) PKM combine (stage-2 stable-L).
// ---------------------------------------------------------------------------
__global__ __launch_bounds__(256) void k_combine(const uint2* __restrict__ cand,
                                                 float* __restrict__ wout,
                                                 int* __restrict__ iout)
{
    const int g = blockIdx.x * 256 + threadIdx.x;
    if (g >= B_ROWS * 8) return;
    const int row = g >> 3, head = g & 7;

    const uint2* c1 = &cand[((size_t)row * 16 + head * 2) * 8];
    const uint2* c2 = c1 + 8;
    float w1[4], w2[4]; int i1[4], i2[4];
#pragma unroll
    for (int a = 0; a < 4; ++a) {
        w1[a] = __uint_as_float(c1[a].y); i1[a] = (int)c1[a].x;
        w2[a] = __uint_as_float(c2[a].y); i2[a] = (int)c2[a].x;
    }
    float cw[16];
#pragma unroll
    for (int a = 0; a < 4; ++a)
#pragma unroll
        for (int b2 = 0; b2 < 4; ++b2) {
            const float s  = w1[a] + w2[b2];
            const float rv = (s > 0.0f) ? s : 0.0f;
            const int   ii = i1[a] * P_BASE + i2[b2];
            cw[a * 4 + b2] = (ii >= L_LAT) ? -1.0f : rv;
        }
    bool used[16];
#pragma unroll
    for (int f = 0; f < 16; ++f) used[f] = false;
    for (int j = 0; j < 4; ++j) {
        int bf = -1;
        for (int f = 0; f < 16; ++f) {
            if (used[f]) continue;
            if (bf < 0 || cw[f] > cw[bf]) bf = f;    // ties -> lower flat
        }
        used[bf] = true;
        const int a = bf >> 2, b2 = bf & 3;
        const int ii = i1[a] * P_BASE + i2[b2];
        float wf = cw[bf];
        int ifin;
        if (ii >= L_LAT) { wf = wf * 0.0f; ifin = L_LAT - 1; }
        else             { ifin = ii; }
        wout[((size_t)row * 8 + head) * 4 + j] = wf;
        iout[((size_t)row * 8 + head) * 4 + j] = ifin;
    }
}

// ---------------------------------------------------------------------------
// Kernel 5: stage-3 exact np.argsort(-w32) per row.
// ---------------------------------------------------------------------------
__global__ __launch_bounds__(64) void k_final(const float* __restrict__ wout,
                                              const int* __restrict__ iout,
                                              float* __restrict__ out)
{
    const int row = blockIdx.x * 64 + threadIdx.x;
    if (row >= B_ROWS) return;

    float w[32]; int idx[32]; int tosort[32];
    for (int j = 0; j < 32; ++j) {
        w[j]      = wout[(size_t)row * 32 + j];
        idx[j]    = iout[(size_t)row * 32 + j];
        tosort[j] = j;
    }
    npy_aqs_desc(w, tosort, 32);
    for (int j = 0; j < 32; ++j) {
        const int s = tosort[j];
        out[(size_t)row * 32 + j]                       = w[s];
        out[(size_t)B_ROWS * 32 + (size_t)row * 32 + j] = (float)idx[s];
    }
}

// ---------------------------------------------------------------------------
extern "C" void kernel_launch(void* const* d_in, const int* in_sizes, int n_in,
                              void* d_out, int out_size, void* d_ws, size_t ws_size,
                              hipStream_t stream)
{
    const float* x    = (const float*)d_in[0];
    const float* Wm   = (const float*)d_in[1];
    const float* bias = (const float*)d_in[2];
    float* out = (float*)d_out;

    const size_t xbBytes   = (size_t)B_ROWS * D_INN * 2;
    const size_t wbBytes   = (size_t)N_COL * D_INN * 2;
    const size_t candBytes = (size_t)B_ROWS * 16 * 8 * sizeof(uint2);
    const size_t flagBytes = (size_t)B_ROWS * 16 * sizeof(int);
    const size_t woutBytes = (size_t)B_ROWS * 32 * sizeof(float);
    const size_t ioutBytes = (size_t)B_ROWS * 32 * sizeof(int);
    const size_t fixedBytes = xbBytes + wbBytes + candBytes + flagBytes + woutBytes + ioutBytes;

    int CH = B_ROWS;
    while (CH > 128 && (size_t)CH * N_COL * sizeof(float) + fixedBytes > ws_size)
        CH >>= 1;

    char*     wsb   = (char*)d_ws;
    float*    xs    = (float*)wsb;
    ushort_t* xb    = (ushort_t*)(wsb + (size_t)CH * N_COL * sizeof(float));
    ushort_t* wb    = (ushort_t*)((char*)xb + xbBytes);
    uint2*    cand  = (uint2*)((char*)wb + wbBytes);
    int*      flags = (int*)((char*)cand + candBytes);
    float*    wout  = (float*)((char*)flags + flagBytes);
    int*      iout  = (int*)((char*)wout + woutBytes);

    k_prep<<<1024, 256, 0, stream>>>(x, Wm, xb, wb);

    for (int row0 = 0; row0 < B_ROWS; row0 += CH) {
        dim3 grid(CH / 128, N_COL / 128);
        k_mfma<<<grid, 256, 0, stream>>>(xb, wb, bias, xs, row0);
        k_top8<<<CH * 16, 64, 0, stream>>>(xs, cand, row0);
    }
    k_refine<<<B_ROWS, 128, 0, stream>>>(x, Wm, bias, cand, flags);
    k_exact1024<<<B_ROWS * 16, 256, 0, stream>>>(x, Wm, bias, cand, flags);
    k_combine<<<(B_ROWS * 8 + 255) / 256, 256, 0, stream>>>(cand, wout, iout);
    k_final<<<(B_ROWS + 63) / 64, 64, 0, stream>>>(wout, iout, out);
}

// Round 17
// 4247.215 us; speedup vs baseline: 2.6181x; 1.0165x over previous
//
#include <hip/hip_runtime.h>

#define B_ROWS 8192
#define D_INN  2048
#define N_COL  16384
#define P_BASE 1024
#define L_LAT  600000

typedef unsigned short ushort_t;
typedef unsigned long long u64_t;
typedef __attribute__((ext_vector_type(8))) __bf16 bf16x8;
typedef __attribute__((ext_vector_type(4))) float  f32x4;

// ---------------------------------------------------------------------------
// numpy aquicksort (introsort, argsort variant) with LT(a,b) := (b<a):
// exactly np.argsort(-x).  Scalar version (used for the 32-element stage-3).
// ---------------------------------------------------------------------------
#define NPY_LT(a, b) ((b) < (a))
__device__ void npy_aqs_desc(const float* __restrict__ v, int* tosort, int n)
{
    const int SMALL = 15;
    int stack[64]; int sp = 0;
    int pl = 0, pr = n - 1;
    for (;;) {
        while (pr - pl > SMALL) {
            const int pm = pl + ((pr - pl) >> 1);
            if (NPY_LT(v[tosort[pm]], v[tosort[pl]])) { int t = tosort[pm]; tosort[pm] = tosort[pl]; tosort[pl] = t; }
            if (NPY_LT(v[tosort[pr]], v[tosort[pm]])) { int t = tosort[pr]; tosort[pr] = tosort[pm]; tosort[pm] = t; }
            if (NPY_LT(v[tosort[pm]], v[tosort[pl]])) { int t = tosort[pm]; tosort[pm] = tosort[pl]; tosort[pl] = t; }
            const float vp = v[tosort[pm]];
            int pi = pl;
            int pj = pr - 1;
            { int t = tosort[pm]; tosort[pm] = tosort[pj]; tosort[pj] = t; }
            for (;;) {
                do { ++pi; } while (NPY_LT(v[tosort[pi]], vp));
                do { --pj; } while (NPY_LT(vp, v[tosort[pj]]));
                if (pi >= pj) break;
                int t = tosort[pi]; tosort[pi] = tosort[pj]; tosort[pj] = t;
            }
            const int pk = pr - 1;
            { int t = tosort[pi]; tosort[pi] = tosort[pk]; tosort[pk] = t; }
            if (pi - pl < pr - pi) { stack[sp++] = pi + 1; stack[sp++] = pr;     pr = pi - 1; }
            else                   { stack[sp++] = pl;     stack[sp++] = pi - 1; pl = pi + 1; }
        }
        for (int i = pl + 1; i <= pr; ++i) {
            const int vi = tosort[i];
            const float vp = v[vi];
            int j = i;
            while (j > pl && NPY_LT(vp, v[tosort[j - 1]])) { tosort[j] = tosort[j - 1]; --j; }
            tosort[j] = vi;
        }
        if (sp == 0) break;
        pr = stack[--sp]; pl = stack[--sp];
    }
}

// ---------------------------------------------------------------------------
// Latency-optimized, permutation-exact emulation of the same algorithm on
// 1024 packed LDS keys ((f32 bits)<<32 | idx).  Three bit-exact transforms:
//  - packets swap as u64 (1 LDS read per visit, not 2 dependent),
//  - partition scans batched 8-wide (no swaps occur mid-scan, so LDS state
//    equals the serial view; stop = first failing slot, identical to serial),
//  - leaf insertion-sort replaced by a 16-wide sorting network on
//    (desc-monotone value, leaf slot) = the same stable permutation.
// ---------------------------------------------------------------------------
__device__ inline float kval(u64_t k) { return __uint_as_float((unsigned)(k >> 32)); }

__device__ void fast_aqs_desc_1024(u64_t* __restrict__ keys)
{
    const int SMALL = 15;
    int stack[64]; int sp = 0;
    int pl = 0, pr = P_BASE - 1;
    for (;;) {
        while (pr - pl > SMALL) {
            const int pm = pl + ((pr - pl) >> 1);
            if (kval(keys[pl]) < kval(keys[pm])) { u64_t t = keys[pm]; keys[pm] = keys[pl]; keys[pl] = t; }
            if (kval(keys[pm]) < kval(keys[pr])) { u64_t t = keys[pr]; keys[pr] = keys[pm]; keys[pm] = t; }
            if (kval(keys[pl]) < kval(keys[pm])) { u64_t t = keys[pm]; keys[pm] = keys[pl]; keys[pl] = t; }
            const float vp = kval(keys[pm]);
            int pi = pl;
            int pj = pr - 1;
            { u64_t t = keys[pm]; keys[pm] = keys[pj]; keys[pj] = t; }
            for (;;) {
                // left scan: advance while val > vp (== do{++pi}while(NPY_LT(v[pi],vp)))
                ++pi;
                for (;;) {
                    if (pi + 7 <= P_BASE - 1) {
                        u64_t kk[8];
#pragma unroll
                        for (int z = 0; z < 8; ++z) kk[z] = keys[pi + z];
                        int stop = 8;
#pragma unroll
                        for (int z = 7; z >= 0; --z) if (!(kval(kk[z]) > vp)) stop = z;
                        if (stop < 8) { pi += stop; break; }
                        pi += 8;
                    } else {
                        while (kval(keys[pi]) > vp) ++pi;
                        break;
                    }
                }
                // right scan: advance while val < vp
                --pj;
                for (;;) {
                    if (pj >= 7) {
                        u64_t kk[8];
#pragma unroll
                        for (int z = 0; z < 8; ++z) kk[z] = keys[pj - z];
                        int stop = 8;
#pragma unroll
                        for (int z = 7; z >= 0; --z) if (!(kval(kk[z]) < vp)) stop = z;
                        if (stop < 8) { pj -= stop; break; }
                        pj -= 8;
                    } else {
                        while (kval(keys[pj]) < vp) --pj;
                        break;
                    }
                }
                if (pi >= pj) break;
                { u64_t t = keys[pi]; keys[pi] = keys[pj]; keys[pj] = t; }
            }
            { const int pk = pr - 1; u64_t t = keys[pi]; keys[pi] = keys[pk]; keys[pk] = t; }
            if (pi - pl < pr - pi) { stack[sp++] = pi + 1; stack[sp++] = pr;     pr = pi - 1; }
            else                   { stack[sp++] = pl;     stack[sp++] = pi - 1; pl = pi + 1; }
        }
        // leaf: stable descending sort of keys[pl..pr] == numpy insertion result
        const int n = pr - pl + 1;
        if (n >= 2) {
            u64_t nk[16], pay[16];
#pragma unroll
            for (int j = 0; j < 16; ++j) {
                if (j < n) {
                    const u64_t k = keys[pl + j];
                    const unsigned vb = (unsigned)(k >> 32);
                    const unsigned mu = (vb & 0x80000000u) ? ~vb : (vb | 0x80000000u);
                    nk[j]  = ((u64_t)(~mu) << 32) | (unsigned)j;   // desc value, asc slot
                    pay[j] = k;
                } else { nk[j] = ~0ull; pay[j] = 0ull; }
            }
            // Batcher odd-even mergesort network, n=16 (compile-time indices)
#pragma unroll
            for (int p = 1; p < 16; p <<= 1)
#pragma unroll
                for (int k = p; k >= 1; k >>= 1)
#pragma unroll
                    for (int j = k & (p - 1); j + k < 16; j += 2 * k)
#pragma unroll
                        for (int i = 0; i < k; ++i)
                            if (i + j + k < 16)
                                if (((i + j) / (p * 2)) == ((i + j + k) / (p * 2))) {
                                    const int a = i + j, b = i + j + k;
                                    if (nk[a] > nk[b]) {
                                        u64_t t1 = nk[a]; nk[a] = nk[b]; nk[b] = t1;
                                        u64_t t2 = pay[a]; pay[a] = pay[b]; pay[b] = t2;
                                    }
                                }
#pragma unroll
            for (int j = 0; j < 16; ++j)
                if (j < n) keys[pl + j] = pay[j];
        }
        if (sp == 0) break;
        pr = stack[--sp]; pl = stack[--sp];
    }
}

// ---------------------------------------------------------------------------
// Kernel 0: f32 -> bf16 (RNE) copies of x and W.
// ---------------------------------------------------------------------------
__device__ inline unsigned f2b_rne(float f)
{
    const unsigned u = __float_as_uint(f);
    return (u + 0x7FFFu + ((u >> 16) & 1u)) >> 16;
}

__global__ __launch_bounds__(256) void k_prep(const float* __restrict__ x,
                                              const float* __restrict__ Wm,
                                              ushort_t* __restrict__ xb,
                                              ushort_t* __restrict__ wb)
{
    const size_t n1 = (size_t)B_ROWS * D_INN / 4;
    const size_t n2 = (size_t)N_COL * D_INN / 4;
    const size_t stride = (size_t)gridDim.x * blockDim.x;
    for (size_t i = (size_t)blockIdx.x * blockDim.x + threadIdx.x; i < n1 + n2; i += stride) {
        const float4 f = (i < n1) ? reinterpret_cast<const float4*>(x)[i]
                                  : reinterpret_cast<const float4*>(Wm)[i - n1];
        uint2 o;
        o.x = f2b_rne(f.x) | (f2b_rne(f.y) << 16);
        o.y = f2b_rne(f.z) | (f2b_rne(f.w) << 16);
        if (i < n1) reinterpret_cast<uint2*>(xb)[i]      = o;
        else        reinterpret_cast<uint2*>(wb)[i - n1] = o;
    }
}

// ---------------------------------------------------------------------------
// Kernel 1: bf16 MFMA GEMM (shortlist).  128x128 tile, BK=32, 4 waves (2x2),
// staging via global_load_lds width=16 (linear LDS dest == [128][32] layout).
// ---------------------------------------------------------------------------
__global__ __launch_bounds__(256) void k_mfma(const ushort_t* __restrict__ xb,
                                              const ushort_t* __restrict__ wb,
                                              const float* __restrict__ bias,
                                              float* __restrict__ xs, int row0)
{
    __shared__ ushort_t As[128][32];
    __shared__ ushort_t Bs[128][32];
    const int t = threadIdx.x;
    const int bm = blockIdx.x, bn = blockIdx.y;
    const int wid = t >> 6, lane = t & 63;
    const int wm = wid >> 1, wn = wid & 1;
    const int arow0 = row0 + bm * 128;
    const int wrow0 = bn * 128;
    const int l15 = lane & 15, lg = lane >> 4;
    const int sr = lane >> 2;
    const int sc = (lane & 3) * 16;

    f32x4 acc[4][4];
#pragma unroll
    for (int i = 0; i < 4; ++i)
#pragma unroll
        for (int j = 0; j < 4; ++j) acc[i][j] = (f32x4){0.f, 0.f, 0.f, 0.f};

    for (int k0 = 0; k0 < D_INN; k0 += 32) {
#pragma unroll
        for (int e = 0; e < 2; ++e) {
            const int c = wid * 2 + e;
            const char* ga = (const char*)xb +
                (((size_t)(arow0 + c * 16 + sr)) * D_INN + k0) * 2 + sc;
            const char* gb = (const char*)wb +
                (((size_t)(wrow0 + c * 16 + sr)) * D_INN + k0) * 2 + sc;
            __builtin_amdgcn_global_load_lds(
                (const __attribute__((address_space(1))) void*)ga,
                (__attribute__((address_space(3))) void*)((char*)&As[0][0] + c * 1024),
                16, 0, 0);
            __builtin_amdgcn_global_load_lds(
                (const __attribute__((address_space(1))) void*)gb,
                (__attribute__((address_space(3))) void*)((char*)&Bs[0][0] + c * 1024),
                16, 0, 0);
        }
        __syncthreads();
        bf16x8 af[4], bg[4];
#pragma unroll
        for (int i = 0; i < 4; ++i)
            af[i] = __builtin_bit_cast(bf16x8,
                *reinterpret_cast<const uint4*>(&As[wm * 64 + i * 16 + l15][lg * 8]));
#pragma unroll
        for (int j = 0; j < 4; ++j)
            bg[j] = __builtin_bit_cast(bf16x8,
                *reinterpret_cast<const uint4*>(&Bs[wn * 64 + j * 16 + l15][lg * 8]));
#pragma unroll
        for (int i = 0; i < 4; ++i)
#pragma unroll
            for (int j = 0; j < 4; ++j)
                acc[i][j] = __builtin_amdgcn_mfma_f32_16x16x32_bf16(af[i], bg[j], acc[i][j], 0, 0, 0);
        __syncthreads();
    }

#pragma unroll
    for (int i = 0; i < 4; ++i)
#pragma unroll
        for (int j = 0; j < 4; ++j) {
            const int col = wn * 64 + j * 16 + l15;
            const float bj = bias[wrow0 + col];
#pragma unroll
            for (int q = 0; q < 4; ++q) {
                const int rloc = bm * 128 + wm * 64 + i * 16 + lg * 4 + q;
                xs[(size_t)rloc * N_COL + wrow0 + col] = acc[i][j][q] + bj;
            }
        }
}

// ---------------------------------------------------------------------------
// Kernel 2: approx top-6 per (row, head, half).  Shortlist columns only.
// ---------------------------------------------------------------------------
__device__ inline unsigned long long shfl_xor_u64(unsigned long long v, int m)
{
    unsigned lo = __shfl_xor((unsigned)(v & 0xFFFFFFFFull), m, 64);
    unsigned hi = __shfl_xor((unsigned)(v >> 32), m, 64);
    return ((unsigned long long)hi << 32) | lo;
}

__global__ __launch_bounds__(64) void k_top8(const float* __restrict__ xs,
                                             uint2* __restrict__ cand, int row0)
{
    const int blk  = blockIdx.x;
    const int r    = blk >> 4;
    const int h2   = blk & 15;
    const int lane = threadIdx.x;
    const float* src = xs + (size_t)r * N_COL + h2 * P_BASE;

    float v[16];
#pragma unroll
    for (int w = 0; w < 4; ++w) {
        const float4 f = *reinterpret_cast<const float4*>(&src[(lane + w * 64) * 4]);
        v[w * 4 + 0] = f.x; v[w * 4 + 1] = f.y; v[w * 4 + 2] = f.z; v[w * 4 + 3] = f.w;
    }
    uint2* outp = cand + ((size_t)(row0 + r) * 16 + h2) * 8;

    for (int it = 0; it < 6; ++it) {
        unsigned long long best = 0ull;
#pragma unroll
        for (int q = 0; q < 16; ++q) {
            const int col = lane * 4 + (q >> 2) * 256 + (q & 3);
            unsigned ub = __float_as_uint(v[q]);
            ub = (ub & 0x80000000u) ? ~ub : (ub | 0x80000000u);
            const unsigned long long key =
                ((unsigned long long)ub << 32) | (unsigned)(0xFFFFFFFFu - col);
            if (key > best) best = key;
        }
#pragma unroll
        for (int off = 32; off > 0; off >>= 1) {
            const unsigned long long o = shfl_xor_u64(best, off);
            if (o > best) best = o;
        }
        const int col = (int)(0xFFFFFFFFu - (unsigned)(best & 0xFFFFFFFFull));
        if (lane == 0) outp[it] = make_uint2((unsigned)col, 0u);
        const bool own = (lane == ((col & 255) >> 2));
        const int  qi  = ((col >> 8) << 2) | (col & 3);
#pragma unroll
        for (int q = 0; q < 16; ++q)
            if (own && q == qi) v[q] = -__builtin_inff();
    }
}

// ---------------------------------------------------------------------------
// Kernel 3: exact kc=288 recompute of the 6 shortlisted dots per (row, half),
// float4 loads, bit-identical sequential FMA chain; exact stable-L sort of 6;
// write slots 0..5; flag bit-ties among ranks 0..4.
// ---------------------------------------------------------------------------
__global__ __launch_bounds__(128) void k_refine(const float* __restrict__ x,
                                                const float* __restrict__ Wm,
                                                const float* __restrict__ bias,
                                                uint2* __restrict__ cand,
                                                int* __restrict__ flags)
{
    __shared__ float xrow[D_INN];
    __shared__ float sval[96];
    const int row = blockIdx.x;
    const int t   = threadIdx.x;

#pragma unroll
    for (int p = 0; p < 4; ++p)
        *reinterpret_cast<float4*>(&xrow[(t + p * 128) * 4]) =
            *reinterpret_cast<const float4*>(&x[(size_t)row * D_INN + (t + p * 128) * 4]);
    __syncthreads();

    if (t < 96) {
        const int h2 = t / 6, c = t % 6;
        const int col  = (int)cand[((size_t)row * 16 + h2) * 8 + c].x;
        const int wcol = (h2 >> 1) * 2048 + (h2 & 1) * P_BASE + col;
        const float4* wr4 = reinterpret_cast<const float4*>(&Wm[(size_t)wcol * D_INN]);
        const float4* xr4 = reinterpret_cast<const float4*>(xrow);

        float accT = 0.f, accC = 0.f;
        int j4 = 0;
        for (int p = 0; p < 7; ++p) {
#pragma unroll 4
            for (int q = 0; q < 72; ++q, ++j4) {
                const float4 w4 = wr4[j4];
                const float4 x4 = xr4[j4];
                accC = fmaf(x4.x, w4.x, accC);
                accC = fmaf(x4.y, w4.y, accC);
                accC = fmaf(x4.z, w4.z, accC);
                accC = fmaf(x4.w, w4.w, accC);
            }
            accT += accC; accC = 0.f;
        }
#pragma unroll
        for (int q = 0; q < 8; ++q, ++j4) {
            const float4 w4 = wr4[j4];
            const float4 x4 = xr4[j4];
            accC = fmaf(x4.x, w4.x, accC);
            accC = fmaf(x4.y, w4.y, accC);
            accC = fmaf(x4.z, w4.z, accC);
            accC = fmaf(x4.w, w4.w, accC);
        }
        accT += accC;
        sval[t] = accT + bias[wcol];
    }
    __syncthreads();

    if (t < 16) {
        float v[6]; int cl[6];
        for (int s = 0; s < 6; ++s) {
            v[s]  = sval[t * 6 + s];
            cl[s] = (int)cand[((size_t)row * 16 + t) * 8 + s].x;
        }
        for (int a = 0; a < 6; ++a) {
            int b = a;
            for (int q = a + 1; q < 6; ++q)
                if (v[q] > v[b] || (v[q] == v[b] && cl[q] < cl[b])) b = q;
            float tv = v[a]; v[a] = v[b]; v[b] = tv;
            int   tc = cl[a]; cl[a] = cl[b]; cl[b] = tc;
        }
        uint2* outp = &cand[((size_t)row * 16 + t) * 8];
        int flag = 0;
        for (int s = 0; s < 6; ++s) outp[s] = make_uint2((unsigned)cl[s], __float_as_uint(v[s]));
        for (int s = 0; s < 4; ++s)
            if (__float_as_uint(v[s]) == __float_as_uint(v[s + 1])) flag = 1;
        flags[(size_t)row * 16 + t] = flag;
    }
}

// ---------------------------------------------------------------------------
// Kernel 3b: flagged halves -> exact 1024 dots + latency-optimized exact
// introsort emulation on packed LDS keys; write top-4.
// ---------------------------------------------------------------------------
__global__ __launch_bounds__(256) void k_exact1024(const float* __restrict__ x,
                                                   const float* __restrict__ Wm,
                                                   const float* __restrict__ bias,
                                                   uint2* __restrict__ cand,
                                                   const int* __restrict__ flags)
{
    const int rh = blockIdx.x;
    if (!flags[rh]) return;
    __shared__ float xrow[D_INN];
    __shared__ u64_t keys[P_BASE];
    const int row = rh >> 4, h2 = rh & 15;
    const int t = threadIdx.x;

#pragma unroll
    for (int p = 0; p < 2; ++p)
        *reinterpret_cast<float4*>(&xrow[(t + p * 256) * 4]) =
            *reinterpret_cast<const float4*>(&x[(size_t)row * D_INN + (t + p * 256) * 4]);
    __syncthreads();

    const int wbase = (h2 >> 1) * 2048 + (h2 & 1) * P_BASE;
    for (int cc = 0; cc < 4; ++cc) {
        const int col = t + cc * 256;
        const float* wr = &Wm[(size_t)(wbase + col) * D_INN];
        float accT = 0.f, accC = 0.f;
        int j = 0;
        for (int p = 0; p < 7; ++p) {
            for (int q = 0; q < 288; ++q, ++j) accC = fmaf(xrow[j], wr[j], accC);
            accT += accC; accC = 0.f;
        }
        for (; j < D_INN; ++j) accC = fmaf(xrow[j], wr[j], accC);
        accT += accC;
        const float vv = accT + bias[wbase + col];
        keys[col] = ((u64_t)__float_as_uint(vv) << 32) | (unsigned)col;
    }
    __syncthreads();
    if (t == 0) {
        fast_aqs_desc_1024(keys);
        uint2* outp = &cand[(size_t)rh * 8];
        for (int s = 0; s < 4; ++s) {
            const u64_t k = keys[s];
            outp[s] = make_uint2((unsigned)(k & 0xFFFFFFFFull), (unsigned)(k >> 32));
        }
    }
}

// ---------------------------------------------------------------------------
// Kernel 4: per-(row,head) PKM combine (stage-2 stable-L).
// ---------------------------------------------------------------------------
__global__ __launch_bounds__(256) void k_combine(const uint2* __restrict__ cand,
                                                 float* __restrict__ wout,
                                                 int* __restrict__ iout)
{
    const int g = blockIdx.x * 256 + threadIdx.x;
    if (g >= B_ROWS * 8) return;
    const int row = g >> 3, head = g & 7;

    const uint2* c1 = &cand[((size_t)row * 16 + head * 2) * 8];
    const uint2* c2 = c1 + 8;
    float w1[4], w2[4]; int i1[4], i2[4];
#pragma unroll
    for (int a = 0; a < 4; ++a) {
        w1[a] = __uint_as_float(c1[a].y); i1[a] = (int)c1[a].x;
        w2[a] = __uint_as_float(c2[a].y); i2[a] = (int)c2[a].x;
    }
    float cw[16];
#pragma unroll
    for (int a = 0; a < 4; ++a)
#pragma unroll
        for (int b2 = 0; b2 < 4; ++b2) {
            const float s  = w1[a] + w2[b2];
            const float rv = (s > 0.0f) ? s : 0.0f;
            const int   ii = i1[a] * P_BASE + i2[b2];
            cw[a * 4 + b2] = (ii >= L_LAT) ? -1.0f : rv;
        }
    bool used[16];
#pragma unroll
    for (int f = 0; f < 16; ++f) used[f] = false;
    for (int j = 0; j < 4; ++j) {
        int bf = -1;
        for (int f = 0; f < 16; ++f) {
            if (used[f]) continue;
            if (bf < 0 || cw[f] > cw[bf]) bf = f;
        }
        used[bf] = true;
        const int a = bf >> 2, b2 = bf & 3;
        const int ii = i1[a] * P_BASE + i2[b2];
        float wf = cw[bf];
        int ifin;
        if (ii >= L_LAT) { wf = wf * 0.0f; ifin = L_LAT - 1; }
        else             { ifin = ii; }
        wout[((size_t)row * 8 + head) * 4 + j] = wf;
        iout[((size_t)row * 8 + head) * 4 + j] = ifin;
    }
}

// ---------------------------------------------------------------------------
// Kernel 5: stage-3 exact np.argsort(-w32) per row.
// ---------------------------------------------------------------------------
__global__ __launch_bounds__(64) void k_final(const float* __restrict__ wout,
                                              const int* __restrict__ iout,
                                              float* __restrict__ out)
{
    const int row = blockIdx.x * 64 + threadIdx.x;
    if (row >= B_ROWS) return;

    float w[32]; int idx[32]; int tosort[32];
    for (int j = 0; j < 32; ++j) {
        w[j]      = wout[(size_t)row * 32 + j];
        idx[j]    = iout[(size_t)row * 32 + j];
        tosort[j] = j;
    }
    npy_aqs_desc(w, tosort, 32);
    for (int j = 0; j < 32; ++j) {
        const int s = tosort[j];
        out[(size_t)row * 32 + j]                       = w[s];
        out[(size_t)B_ROWS * 32 + (size_t)row * 32 + j] = (float)idx[s];
    }
}

// ---------------------------------------------------------------------------
extern "C" void kernel_launch(void* const* d_in, const int* in_sizes, int n_in,
                              void* d_out, int out_size, void* d_ws, size_t ws_size,
                              hipStream_t stream)
{
    const float* x    = (const float*)d_in[0];
    const float* Wm   = (const float*)d_in[1];
    const float* bias = (const float*)d_in[2];
    float* out = (float*)d_out;

    const size_t xbBytes   = (size_t)B_ROWS * D_INN * 2;
    const size_t wbBytes   = (size_t)N_COL * D_INN * 2;
    const size_t candBytes = (size_t)B_ROWS * 16 * 8 * sizeof(uint2);
    const size_t flagBytes = (size_t)B_ROWS * 16 * sizeof(int);
    const size_t woutBytes = (size_t)B_ROWS * 32 * sizeof(float);
    const size_t ioutBytes = (size_t)B_ROWS * 32 * sizeof(int);
    const size_t fixedBytes = xbBytes + wbBytes + candBytes + flagBytes + woutBytes + ioutBytes;

    int CH = B_ROWS;
    while (CH > 128 && (size_t)CH * N_COL * sizeof(float) + fixedBytes > ws_size)
        CH >>= 1;

    char*     wsb   = (char*)d_ws;
    float*    xs    = (float*)wsb;
    ushort_t* xb    = (ushort_t*)(wsb + (size_t)CH * N_COL * sizeof(float));
    ushort_t* wb    = (ushort_t*)((char*)xb + xbBytes);
    uint2*    cand  = (uint2*)((char*)wb + wbBytes);
    int*      flags = (int*)((char*)cand + candBytes);
    float*    wout  = (float*)((char*)flags + flagBytes);
    int*      iout  = (int*)((char*)wout + woutBytes);

    k_prep<<<1024, 256, 0, stream>>>(x, Wm, xb, wb);

    for (int row0 = 0; row0 < B_ROWS; row0 += CH) {
        dim3 grid(CH / 128, N_COL / 128);
        k_mfma<<<grid, 256, 0, stream>>>(xb, wb, bias, xs, row0);
        k_top8<<<CH * 16, 64, 0, stream>>>(xs, cand, row0);
    }
    k_refine<<<B_ROWS, 128, 0, stream>>>(x, Wm, bias, cand, flags);
    k_exact1024<<<B_ROWS * 16, 256, 0, stream>>>(x, Wm, bias, cand, flags);
    k_combine<<<(B_ROWS * 8 + 255) / 256, 256, 0, stream>>>(cand, wout, iout);
    k_final<<<(B_ROWS + 63) / 64, 64, 0, stream>>>(wout, iout, out);
}

// Round 18
// 4244.232 us; speedup vs baseline: 2.6199x; 1.0007x over previous
//
#include <hip/hip_runtime.h>

#define B_ROWS 8192
#define D_INN  2048
#define N_COL  16384
#define P_BASE 1024
#define L_LAT  600000

typedef unsigned short ushort_t;
typedef unsigned long long u64_t;
typedef __attribute__((ext_vector_type(8))) __bf16 bf16x8;
typedef __attribute__((ext_vector_type(4))) float  f32x4;

// ---------------------------------------------------------------------------
// numpy aquicksort (introsort, argsort variant) with LT(a,b) := (b<a):
// exactly np.argsort(-x).  Scalar version (used for the 32-element stage-3).
// ---------------------------------------------------------------------------
#define NPY_LT(a, b) ((b) < (a))
__device__ void npy_aqs_desc(const float* __restrict__ v, int* tosort, int n)
{
    const int SMALL = 15;
    int stack[64]; int sp = 0;
    int pl = 0, pr = n - 1;
    for (;;) {
        while (pr - pl > SMALL) {
            const int pm = pl + ((pr - pl) >> 1);
            if (NPY_LT(v[tosort[pm]], v[tosort[pl]])) { int t = tosort[pm]; tosort[pm] = tosort[pl]; tosort[pl] = t; }
            if (NPY_LT(v[tosort[pr]], v[tosort[pm]])) { int t = tosort[pr]; tosort[pr] = tosort[pm]; tosort[pm] = t; }
            if (NPY_LT(v[tosort[pm]], v[tosort[pl]])) { int t = tosort[pm]; tosort[pm] = tosort[pl]; tosort[pl] = t; }
            const float vp = v[tosort[pm]];
            int pi = pl;
            int pj = pr - 1;
            { int t = tosort[pm]; tosort[pm] = tosort[pj]; tosort[pj] = t; }
            for (;;) {
                do { ++pi; } while (NPY_LT(v[tosort[pi]], vp));
                do { --pj; } while (NPY_LT(vp, v[tosort[pj]]));
                if (pi >= pj) break;
                int t = tosort[pi]; tosort[pi] = tosort[pj]; tosort[pj] = t;
            }
            const int pk = pr - 1;
            { int t = tosort[pi]; tosort[pi] = tosort[pk]; tosort[pk] = t; }
            if (pi - pl < pr - pi) { stack[sp++] = pi + 1; stack[sp++] = pr;     pr = pi - 1; }
            else                   { stack[sp++] = pl;     stack[sp++] = pi - 1; pl = pi + 1; }
        }
        for (int i = pl + 1; i <= pr; ++i) {
            const int vi = tosort[i];
            const float vp = v[vi];
            int j = i;
            while (j > pl && NPY_LT(vp, v[tosort[j - 1]])) { tosort[j] = tosort[j - 1]; --j; }
            tosort[j] = vi;
        }
        if (sp == 0) break;
        pr = stack[--sp]; pl = stack[--sp];
    }
}

// ---------------------------------------------------------------------------
// Latency-optimized, permutation-exact emulation of the same algorithm on
// 1024 packed LDS keys ((f32 bits)<<32 | idx).
// ---------------------------------------------------------------------------
__device__ inline float kval(u64_t k) { return __uint_as_float((unsigned)(k >> 32)); }

__device__ void fast_aqs_desc_1024(u64_t* __restrict__ keys)
{
    const int SMALL = 15;
    int stack[64]; int sp = 0;
    int pl = 0, pr = P_BASE - 1;
    for (;;) {
        while (pr - pl > SMALL) {
            const int pm = pl + ((pr - pl) >> 1);
            if (kval(keys[pl]) < kval(keys[pm])) { u64_t t = keys[pm]; keys[pm] = keys[pl]; keys[pl] = t; }
            if (kval(keys[pm]) < kval(keys[pr])) { u64_t t = keys[pr]; keys[pr] = keys[pm]; keys[pm] = t; }
            if (kval(keys[pl]) < kval(keys[pm])) { u64_t t = keys[pm]; keys[pm] = keys[pl]; keys[pl] = t; }
            const float vp = kval(keys[pm]);
            int pi = pl;
            int pj = pr - 1;
            { u64_t t = keys[pm]; keys[pm] = keys[pj]; keys[pj] = t; }
            for (;;) {
                ++pi;
                for (;;) {
                    if (pi + 7 <= P_BASE - 1) {
                        u64_t kk[8];
#pragma unroll
                        for (int z = 0; z < 8; ++z) kk[z] = keys[pi + z];
                        int stop = 8;
#pragma unroll
                        for (int z = 7; z >= 0; --z) if (!(kval(kk[z]) > vp)) stop = z;
                        if (stop < 8) { pi += stop; break; }
                        pi += 8;
                    } else {
                        while (kval(keys[pi]) > vp) ++pi;
                        break;
                    }
                }
                --pj;
                for (;;) {
                    if (pj >= 7) {
                        u64_t kk[8];
#pragma unroll
                        for (int z = 0; z < 8; ++z) kk[z] = keys[pj - z];
                        int stop = 8;
#pragma unroll
                        for (int z = 7; z >= 0; --z) if (!(kval(kk[z]) < vp)) stop = z;
                        if (stop < 8) { pj -= stop; break; }
                        pj -= 8;
                    } else {
                        while (kval(keys[pj]) < vp) --pj;
                        break;
                    }
                }
                if (pi >= pj) break;
                { u64_t t = keys[pi]; keys[pi] = keys[pj]; keys[pj] = t; }
            }
            { const int pk = pr - 1; u64_t t = keys[pi]; keys[pi] = keys[pk]; keys[pk] = t; }
            if (pi - pl < pr - pi) { stack[sp++] = pi + 1; stack[sp++] = pr;     pr = pi - 1; }
            else                   { stack[sp++] = pl;     stack[sp++] = pi - 1; pl = pi + 1; }
        }
        const int n = pr - pl + 1;
        if (n >= 2) {
            u64_t nk[16], pay[16];
#pragma unroll
            for (int j = 0; j < 16; ++j) {
                if (j < n) {
                    const u64_t k = keys[pl + j];
                    const unsigned vb = (unsigned)(k >> 32);
                    const unsigned mu = (vb & 0x80000000u) ? ~vb : (vb | 0x80000000u);
                    nk[j]  = ((u64_t)(~mu) << 32) | (unsigned)j;
                    pay[j] = k;
                } else { nk[j] = ~0ull; pay[j] = 0ull; }
            }
#pragma unroll
            for (int p = 1; p < 16; p <<= 1)
#pragma unroll
                for (int k = p; k >= 1; k >>= 1)
#pragma unroll
                    for (int j = k & (p - 1); j + k < 16; j += 2 * k)
#pragma unroll
                        for (int i = 0; i < k; ++i)
                            if (i + j + k < 16)
                                if (((i + j) / (p * 2)) == ((i + j + k) / (p * 2))) {
                                    const int a = i + j, b = i + j + k;
                                    if (nk[a] > nk[b]) {
                                        u64_t t1 = nk[a]; nk[a] = nk[b]; nk[b] = t1;
                                        u64_t t2 = pay[a]; pay[a] = pay[b]; pay[b] = t2;
                                    }
                                }
#pragma unroll
            for (int j = 0; j < 16; ++j)
                if (j < n) keys[pl + j] = pay[j];
        }
        if (sp == 0) break;
        pr = stack[--sp]; pl = stack[--sp];
    }
}

// ---------------------------------------------------------------------------
// Kernel 0: f32 -> bf16 (RNE) copies of x and W.
// ---------------------------------------------------------------------------
__device__ inline unsigned f2b_rne(float f)
{
    const unsigned u = __float_as_uint(f);
    return (u + 0x7FFFu + ((u >> 16) & 1u)) >> 16;
}

__global__ __launch_bounds__(256) void k_prep(const float* __restrict__ x,
                                              const float* __restrict__ Wm,
                                              ushort_t* __restrict__ xb,
                                              ushort_t* __restrict__ wb)
{
    const size_t n1 = (size_t)B_ROWS * D_INN / 4;
    const size_t n2 = (size_t)N_COL * D_INN / 4;
    const size_t stride = (size_t)gridDim.x * blockDim.x;
    for (size_t i = (size_t)blockIdx.x * blockDim.x + threadIdx.x; i < n1 + n2; i += stride) {
        const float4 f = (i < n1) ? reinterpret_cast<const float4*>(x)[i]
                                  : reinterpret_cast<const float4*>(Wm)[i - n1];
        uint2 o;
        o.x = f2b_rne(f.x) | (f2b_rne(f.y) << 16);
        o.y = f2b_rne(f.z) | (f2b_rne(f.w) << 16);
        if (i < n1) reinterpret_cast<uint2*>(xb)[i]      = o;
        else        reinterpret_cast<uint2*>(wb)[i - n1] = o;
    }
}

// ---------------------------------------------------------------------------
// Kernel 1: bf16 MFMA GEMM (shortlist).  128x128 tile, BK=32, 4 waves (2x2),
// staging via global_load_lds width=16 (linear LDS dest == [128][32] layout).
// ---------------------------------------------------------------------------
__global__ __launch_bounds__(256) void k_mfma(const ushort_t* __restrict__ xb,
                                              const ushort_t* __restrict__ wb,
                                              const float* __restrict__ bias,
                                              float* __restrict__ xs, int row0)
{
    __shared__ ushort_t As[128][32];
    __shared__ ushort_t Bs[128][32];
    const int t = threadIdx.x;
    const int bm = blockIdx.x, bn = blockIdx.y;
    const int wid = t >> 6, lane = t & 63;
    const int wm = wid >> 1, wn = wid & 1;
    const int arow0 = row0 + bm * 128;
    const int wrow0 = bn * 128;
    const int l15 = lane & 15, lg = lane >> 4;
    const int sr = lane >> 2;
    const int sc = (lane & 3) * 16;

    f32x4 acc[4][4];
#pragma unroll
    for (int i = 0; i < 4; ++i)
#pragma unroll
        for (int j = 0; j < 4; ++j) acc[i][j] = (f32x4){0.f, 0.f, 0.f, 0.f};

    for (int k0 = 0; k0 < D_INN; k0 += 32) {
#pragma unroll
        for (int e = 0; e < 2; ++e) {
            const int c = wid * 2 + e;
            const char* ga = (const char*)xb +
                (((size_t)(arow0 + c * 16 + sr)) * D_INN + k0) * 2 + sc;
            const char* gb = (const char*)wb +
                (((size_t)(wrow0 + c * 16 + sr)) * D_INN + k0) * 2 + sc;
            __builtin_amdgcn_global_load_lds(
                (const __attribute__((address_space(1))) void*)ga,
                (__attribute__((address_space(3))) void*)((char*)&As[0][0] + c * 1024),
                16, 0, 0);
            __builtin_amdgcn_global_load_lds(
                (const __attribute__((address_space(1))) void*)gb,
                (__attribute__((address_space(3))) void*)((char*)&Bs[0][0] + c * 1024),
                16, 0, 0);
        }
        __syncthreads();
        bf16x8 af[4], bg[4];
#pragma unroll
        for (int i = 0; i < 4; ++i)
            af[i] = __builtin_bit_cast(bf16x8,
                *reinterpret_cast<const uint4*>(&As[wm * 64 + i * 16 + l15][lg * 8]));
#pragma unroll
        for (int j = 0; j < 4; ++j)
            bg[j] = __builtin_bit_cast(bf16x8,
                *reinterpret_cast<const uint4*>(&Bs[wn * 64 + j * 16 + l15][lg * 8]));
#pragma unroll
        for (int i = 0; i < 4; ++i)
#pragma unroll
            for (int j = 0; j < 4; ++j)
                acc[i][j] = __builtin_amdgcn_mfma_f32_16x16x32_bf16(af[i], bg[j], acc[i][j], 0, 0, 0);
        __syncthreads();
    }

#pragma unroll
    for (int i = 0; i < 4; ++i)
#pragma unroll
        for (int j = 0; j < 4; ++j) {
            const int col = wn * 64 + j * 16 + l15;
            const float bj = bias[wrow0 + col];
#pragma unroll
            for (int q = 0; q < 4; ++q) {
                const int rloc = bm * 128 + wm * 64 + i * 16 + lg * 4 + q;
                xs[(size_t)rloc * N_COL + wrow0 + col] = acc[i][j][q] + bj;
            }
        }
}

// ---------------------------------------------------------------------------
// Kernel 2: approx top-6 per (row, head, half).  Shortlist columns only.
// ---------------------------------------------------------------------------
__device__ inline unsigned long long shfl_xor_u64(unsigned long long v, int m)
{
    unsigned lo = __shfl_xor((unsigned)(v & 0xFFFFFFFFull), m, 64);
    unsigned hi = __shfl_xor((unsigned)(v >> 32), m, 64);
    return ((unsigned long long)hi << 32) | lo;
}

__global__ __launch_bounds__(64) void k_top8(const float* __restrict__ xs,
                                             uint2* __restrict__ cand, int row0)
{
    const int blk  = blockIdx.x;
    const int r    = blk >> 4;
    const int h2   = blk & 15;
    const int lane = threadIdx.x;
    const float* src = xs + (size_t)r * N_COL + h2 * P_BASE;

    float v[16];
#pragma unroll
    for (int w = 0; w < 4; ++w) {
        const float4 f = *reinterpret_cast<const float4*>(&src[(lane + w * 64) * 4]);
        v[w * 4 + 0] = f.x; v[w * 4 + 1] = f.y; v[w * 4 + 2] = f.z; v[w * 4 + 3] = f.w;
    }
    uint2* outp = cand + ((size_t)(row0 + r) * 16 + h2) * 8;

    for (int it = 0; it < 6; ++it) {
        unsigned long long best = 0ull;
#pragma unroll
        for (int q = 0; q < 16; ++q) {
            const int col = lane * 4 + (q >> 2) * 256 + (q & 3);
            unsigned ub = __float_as_uint(v[q]);
            ub = (ub & 0x80000000u) ? ~ub : (ub | 0x80000000u);
            const unsigned long long key =
                ((unsigned long long)ub << 32) | (unsigned)(0xFFFFFFFFu - col);
            if (key > best) best = key;
        }
#pragma unroll
        for (int off = 32; off > 0; off >>= 1) {
            const unsigned long long o = shfl_xor_u64(best, off);
            if (o > best) best = o;
        }
        const int col = (int)(0xFFFFFFFFu - (unsigned)(best & 0xFFFFFFFFull));
        if (lane == 0) outp[it] = make_uint2((unsigned)col, 0u);
        const bool own = (lane == ((col & 255) >> 2));
        const int  qi  = ((col >> 8) << 2) | (col & 3);
#pragma unroll
        for (int q = 0; q < 16; ++q)
            if (own && q == qi) v[q] = -__builtin_inff();
    }
}

// ---------------------------------------------------------------------------
// Kernel 3: exact kc=288 recompute of the 6 shortlisted dots per (row, half),
// float4 loads, bit-identical sequential FMA chain; exact stable-L sort of 6;
// write slots 0..5; flag bit-ties among ranks 0..4.
// ---------------------------------------------------------------------------
__global__ __launch_bounds__(128) void k_refine(const float* __restrict__ x,
                                                const float* __restrict__ Wm,
                                                const float* __restrict__ bias,
                                                uint2* __restrict__ cand,
                                                int* __restrict__ flags)
{
    __shared__ float xrow[D_INN];
    __shared__ float sval[96];
    const int row = blockIdx.x;
    const int t   = threadIdx.x;

#pragma unroll
    for (int p = 0; p < 4; ++p)
        *reinterpret_cast<float4*>(&xrow[(t + p * 128) * 4]) =
            *reinterpret_cast<const float4*>(&x[(size_t)row * D_INN + (t + p * 128) * 4]);
    __syncthreads();

    if (t < 96) {
        const int h2 = t / 6, c = t % 6;
        const int col  = (int)cand[((size_t)row * 16 + h2) * 8 + c].x;
        const int wcol = (h2 >> 1) * 2048 + (h2 & 1) * P_BASE + col;
        const float4* wr4 = reinterpret_cast<const float4*>(&Wm[(size_t)wcol * D_INN]);
        const float4* xr4 = reinterpret_cast<const float4*>(xrow);

        float accT = 0.f, accC = 0.f;
        int j4 = 0;
        for (int p = 0; p < 7; ++p) {
#pragma unroll 4
            for (int q = 0; q < 72; ++q, ++j4) {
                const float4 w4 = wr4[j4];
                const float4 x4 = xr4[j4];
                accC = fmaf(x4.x, w4.x, accC);
                accC = fmaf(x4.y, w4.y, accC);
                accC = fmaf(x4.z, w4.z, accC);
                accC = fmaf(x4.w, w4.w, accC);
            }
            accT += accC; accC = 0.f;
        }
#pragma unroll
        for (int q = 0; q < 8; ++q, ++j4) {
            const float4 w4 = wr4[j4];
            const float4 x4 = xr4[j4];
            accC = fmaf(x4.x, w4.x, accC);
            accC = fmaf(x4.y, w4.y, accC);
            accC = fmaf(x4.z, w4.z, accC);
            accC = fmaf(x4.w, w4.w, accC);
        }
        accT += accC;
        sval[t] = accT + bias[wcol];
    }
    __syncthreads();

    if (t < 16) {
        float v[6]; int cl[6];
        for (int s = 0; s < 6; ++s) {
            v[s]  = sval[t * 6 + s];
            cl[s] = (int)cand[((size_t)row * 16 + t) * 8 + s].x;
        }
        for (int a = 0; a < 6; ++a) {
            int b = a;
            for (int q = a + 1; q < 6; ++q)
                if (v[q] > v[b] || (v[q] == v[b] && cl[q] < cl[b])) b = q;
            float tv = v[a]; v[a] = v[b]; v[b] = tv;
            int   tc = cl[a]; cl[a] = cl[b]; cl[b] = tc;
        }
        uint2* outp = &cand[((size_t)row * 16 + t) * 8];
        int flag = 0;
        for (int s = 0; s < 6; ++s) outp[s] = make_uint2((unsigned)cl[s], __float_as_uint(v[s]));
        for (int s = 0; s < 4; ++s)
            if (__float_as_uint(v[s]) == __float_as_uint(v[s + 1])) flag = 1;
        flags[(size_t)row * 16 + t] = flag;
    }
}

// ---------------------------------------------------------------------------
// Kernel 3b: flagged halves -> exact 1024 dots (1 col/thread, float4+unroll,
// 16 waves for MLP) + latency-optimized exact introsort; write top-4.
// ---------------------------------------------------------------------------
__global__ __launch_bounds__(1024) void k_exact1024(const float* __restrict__ x,
                                                    const float* __restrict__ Wm,
                                                    const float* __restrict__ bias,
                                                    uint2* __restrict__ cand,
                                                    const int* __restrict__ flags)
{
    const int rh = blockIdx.x;
    if (!flags[rh]) return;
    __shared__ float xrow[D_INN];
    __shared__ u64_t keys[P_BASE];
    const int row = rh >> 4, h2 = rh & 15;
    const int t = threadIdx.x;

    if (t < 512)
        *reinterpret_cast<float4*>(&xrow[t * 4]) =
            *reinterpret_cast<const float4*>(&x[(size_t)row * D_INN + t * 4]);
    __syncthreads();

    const int wbase = (h2 >> 1) * 2048 + (h2 & 1) * P_BASE;
    {
        const int col = t;
        const float4* wr4 = reinterpret_cast<const float4*>(&Wm[(size_t)(wbase + col) * D_INN]);
        const float4* xr4 = reinterpret_cast<const float4*>(xrow);
        float accT = 0.f, accC = 0.f;
        int j4 = 0;
        for (int p = 0; p < 7; ++p) {              // 7 panels of 288 (72 float4)
#pragma unroll 4
            for (int q = 0; q < 72; ++q, ++j4) {
                const float4 w4 = wr4[j4];
                const float4 x4 = xr4[j4];
                accC = fmaf(x4.x, w4.x, accC);
                accC = fmaf(x4.y, w4.y, accC);
                accC = fmaf(x4.z, w4.z, accC);
                accC = fmaf(x4.w, w4.w, accC);
            }
            accT += accC; accC = 0.f;
        }
#pragma unroll
        for (int q = 0; q < 8; ++q, ++j4) {        // 32-tail
            const float4 w4 = wr4[j4];
            const float4 x4 = xr4[j4];
            accC = fmaf(x4.x, w4.x, accC);
            accC = fmaf(x4.y, w4.y, accC);
            accC = fmaf(x4.z, w4.z, accC);
            accC = fmaf(x4.w, w4.w, accC);
        }
        accT += accC;
        const float vv = accT + bias[wbase + col];
        keys[col] = ((u64_t)__float_as_uint(vv) << 32) | (unsigned)col;
    }
    __syncthreads();
    if (t == 0) {
        fast_aqs_desc_1024(keys);
        uint2* outp = &cand[(size_t)rh * 8];
        for (int s = 0; s < 4; ++s) {
            const u64_t k = keys[s];
            outp[s] = make_uint2((unsigned)(k & 0xFFFFFFFFull), (unsigned)(k >> 32));
        }
    }
}

// ---------------------------------------------------------------------------
// Kernel 4: per-(row,head) PKM combine (stage-2 stable-L).
// ---------------------------------------------------------------------------
__global__ __launch_bounds__(256) void k_combine(const uint2* __restrict__ cand,
                                                 float* __restrict__ wout,
                                                 int* __restrict__ iout)
{
    const int g = blockIdx.x * 256 + threadIdx.x;
    if (g >= B_ROWS * 8) return;
    const int row = g >> 3, head = g & 7;

    const uint2* c1 = &cand[((size_t)row * 16 + head * 2) * 8];
    const uint2* c2 = c1 + 8;
    float w1[4], w2[4]; int i1[4], i2[4];
#pragma unroll
    for (int a = 0; a < 4; ++a) {
        w1[a] = __uint_as_float(c1[a].y); i1[a] = (int)c1[a].x;
        w2[a] = __uint_as_float(c2[a].y); i2[a] = (int)c2[a].x;
    }
    float cw[16];
#pragma unroll
    for (int a = 0; a < 4; ++a)
#pragma unroll
        for (int b2 = 0; b2 < 4; ++b2) {
            const float s  = w1[a] + w2[b2];
            const float rv = (s > 0.0f) ? s : 0.0f;
            const int   ii = i1[a] * P_BASE + i2[b2];
            cw[a * 4 + b2] = (ii >= L_LAT) ? -1.0f : rv;
        }
    bool used[16];
#pragma unroll
    for (int f = 0; f < 16; ++f) used[f] = false;
    for (int j = 0; j < 4; ++j) {
        int bf = -1;
        for (int f = 0; f < 16; ++f) {
            if (used[f]) continue;
            if (bf < 0 || cw[f] > cw[bf]) bf = f;
        }
        used[bf] = true;
        const int a = bf >> 2, b2 = bf & 3;
        const int ii = i1[a] * P_BASE + i2[b2];
        float wf = cw[bf];
        int ifin;
        if (ii >= L_LAT) { wf = wf * 0.0f; ifin = L_LAT - 1; }
        else             { ifin = ii; }
        wout[((size_t)row * 8 + head) * 4 + j] = wf;
        iout[((size_t)row * 8 + head) * 4 + j] = ifin;
    }
}

// ---------------------------------------------------------------------------
// Kernel 5: stage-3 exact np.argsort(-w32) per row.
// ---------------------------------------------------------------------------
__global__ __launch_bounds__(64) void k_final(const float* __restrict__ wout,
                                              const int* __restrict__ iout,
                                              float* __restrict__ out)
{
    const int row = blockIdx.x * 64 + threadIdx.x;
    if (row >= B_ROWS) return;

    float w[32]; int idx[32]; int tosort[32];
    for (int j = 0; j < 32; ++j) {
        w[j]      = wout[(size_t)row * 32 + j];
        idx[j]    = iout[(size_t)row * 32 + j];
        tosort[j] = j;
    }
    npy_aqs_desc(w, tosort, 32);
    for (int j = 0; j < 32; ++j) {
        const int s = tosort[j];
        out[(size_t)row * 32 + j]                       = w[s];
        out[(size_t)B_ROWS * 32 + (size_t)row * 32 + j] = (float)idx[s];
    }
}

// ---------------------------------------------------------------------------
extern "C" void kernel_launch(void* const* d_in, const int* in_sizes, int n_in,
                              void* d_out, int out_size, void* d_ws, size_t ws_size,
                              hipStream_t stream)
{
    const float* x    = (const float*)d_in[0];
    const float* Wm   = (const float*)d_in[1];
    const float* bias = (const float*)d_in[2];
    float* out = (float*)d_out;

    const size_t xbBytes   = (size_t)B_ROWS * D_INN * 2;
    const size_t wbBytes   = (size_t)N_COL * D_INN * 2;
    const size_t candBytes = (size_t)B_ROWS * 16 * 8 * sizeof(uint2);
    const size_t flagBytes = (size_t)B_ROWS * 16 * sizeof(int);
    const size_t woutBytes = (size_t)B_ROWS * 32 * sizeof(float);
    const size_t ioutBytes = (size_t)B_ROWS * 32 * sizeof(int);
    const size_t fixedBytes = xbBytes + wbBytes + candBytes + flagBytes + woutBytes + ioutBytes;

    int CH = B_ROWS;
    while (CH > 128 && (size_t)CH * N_COL * sizeof(float) + fixedBytes > ws_size)
        CH >>= 1;

    char*     wsb   = (char*)d_ws;
    float*    xs    = (float*)wsb;
    ushort_t* xb    = (ushort_t*)(wsb + (size_t)CH * N_COL * sizeof(float));
    ushort_t* wb    = (ushort_t*)((char*)xb + xbBytes);
    uint2*    cand  = (uint2*)((char*)wb + wbBytes);
    int*      flags = (int*)((char*)cand + candBytes);
    float*    wout  = (float*)((char*)flags + flagBytes);
    int*      iout  = (int*)((char*)wout + woutBytes);

    k_prep<<<1024, 256, 0, stream>>>(x, Wm, xb, wb);

    for (int row0 = 0; row0 < B_ROWS; row0 += CH) {
        dim3 grid(CH / 128, N_COL / 128);
        k_mfma<<<grid, 256, 0, stream>>>(xb, wb, bias, xs, row0);
        k_top8<<<CH * 16, 64, 0, stream>>>(xs, cand, row0);
    }
    k_refine<<<B_ROWS, 128, 0, stream>>>(x, Wm, bias, cand, flags);
    k_exact1024<<<B_ROWS * 16, 1024, 0, stream>>>(x, Wm, bias, cand, flags);
    k_combine<<<(B_ROWS * 8 + 255) / 256, 256, 0, stream>>>(cand, wout, iout);
    k_final<<<(B_ROWS + 63) / 64, 64, 0, stream>>>(wout, iout, out);
}

// Round 19
// 4189.339 us; speedup vs baseline: 2.6543x; 1.0131x over previous
//
#include <hip/hip_runtime.h>

#define B_ROWS 8192
#define D_INN  2048
#define N_COL  16384
#define P_BASE 1024
#define L_LAT  600000

typedef unsigned short ushort_t;
typedef unsigned long long u64_t;
typedef __attribute__((ext_vector_type(8))) __bf16 bf16x8;
typedef __attribute__((ext_vector_type(4))) float  f32x4;

// ---------------------------------------------------------------------------
// numpy aquicksort (introsort, argsort variant) with LT(a,b) := (b<a):
// exactly np.argsort(-x).  Scalar version (used for the 32-element stage-3).
// ---------------------------------------------------------------------------
#define NPY_LT(a, b) ((b) < (a))
__device__ void npy_aqs_desc(const float* __restrict__ v, int* tosort, int n)
{
    const int SMALL = 15;
    int stack[64]; int sp = 0;
    int pl = 0, pr = n - 1;
    for (;;) {
        while (pr - pl > SMALL) {
            const int pm = pl + ((pr - pl) >> 1);
            if (NPY_LT(v[tosort[pm]], v[tosort[pl]])) { int t = tosort[pm]; tosort[pm] = tosort[pl]; tosort[pl] = t; }
            if (NPY_LT(v[tosort[pr]], v[tosort[pm]])) { int t = tosort[pr]; tosort[pr] = tosort[pm]; tosort[pm] = t; }
            if (NPY_LT(v[tosort[pm]], v[tosort[pl]])) { int t = tosort[pm]; tosort[pm] = tosort[pl]; tosort[pl] = t; }
            const float vp = v[tosort[pm]];
            int pi = pl;
            int pj = pr - 1;
            { int t = tosort[pm]; tosort[pm] = tosort[pj]; tosort[pj] = t; }
            for (;;) {
                do { ++pi; } while (NPY_LT(v[tosort[pi]], vp));
                do { --pj; } while (NPY_LT(vp, v[tosort[pj]]));
                if (pi >= pj) break;
                int t = tosort[pi]; tosort[pi] = tosort[pj]; tosort[pj] = t;
            }
            const int pk = pr - 1;
            { int t = tosort[pi]; tosort[pi] = tosort[pk]; tosort[pk] = t; }
            if (pi - pl < pr - pi) { stack[sp++] = pi + 1; stack[sp++] = pr;     pr = pi - 1; }
            else                   { stack[sp++] = pl;     stack[sp++] = pi - 1; pl = pi + 1; }
        }
        for (int i = pl + 1; i <= pr; ++i) {
            const int vi = tosort[i];
            const float vp = v[vi];
            int j = i;
            while (j > pl && NPY_LT(vp, v[tosort[j - 1]])) { tosort[j] = tosort[j - 1]; --j; }
            tosort[j] = vi;
        }
        if (sp == 0) break;
        pr = stack[--sp]; pl = stack[--sp];
    }
}

// ---------------------------------------------------------------------------
// Latency-optimized, permutation-exact emulation of the same algorithm on
// 1024 packed LDS keys ((f32 bits)<<32 | idx).
// ---------------------------------------------------------------------------
__device__ inline float kval(u64_t k) { return __uint_as_float((unsigned)(k >> 32)); }

__device__ void fast_aqs_desc_1024(u64_t* __restrict__ keys)
{
    const int SMALL = 15;
    int stack[64]; int sp = 0;
    int pl = 0, pr = P_BASE - 1;
    for (;;) {
        while (pr - pl > SMALL) {
            const int pm = pl + ((pr - pl) >> 1);
            if (kval(keys[pl]) < kval(keys[pm])) { u64_t t = keys[pm]; keys[pm] = keys[pl]; keys[pl] = t; }
            if (kval(keys[pm]) < kval(keys[pr])) { u64_t t = keys[pr]; keys[pr] = keys[pm]; keys[pm] = t; }
            if (kval(keys[pl]) < kval(keys[pm])) { u64_t t = keys[pm]; keys[pm] = keys[pl]; keys[pl] = t; }
            const float vp = kval(keys[pm]);
            int pi = pl;
            int pj = pr - 1;
            { u64_t t = keys[pm]; keys[pm] = keys[pj]; keys[pj] = t; }
            for (;;) {
                ++pi;
                for (;;) {
                    if (pi + 7 <= P_BASE - 1) {
                        u64_t kk[8];
#pragma unroll
                        for (int z = 0; z < 8; ++z) kk[z] = keys[pi + z];
                        int stop = 8;
#pragma unroll
                        for (int z = 7; z >= 0; --z) if (!(kval(kk[z]) > vp)) stop = z;
                        if (stop < 8) { pi += stop; break; }
                        pi += 8;
                    } else {
                        while (kval(keys[pi]) > vp) ++pi;
                        break;
                    }
                }
                --pj;
                for (;;) {
                    if (pj >= 7) {
                        u64_t kk[8];
#pragma unroll
                        for (int z = 0; z < 8; ++z) kk[z] = keys[pj - z];
                        int stop = 8;
#pragma unroll
                        for (int z = 7; z >= 0; --z) if (!(kval(kk[z]) < vp)) stop = z;
                        if (stop < 8) { pj -= stop; break; }
                        pj -= 8;
                    } else {
                        while (kval(keys[pj]) < vp) --pj;
                        break;
                    }
                }
                if (pi >= pj) break;
                { u64_t t = keys[pi]; keys[pi] = keys[pj]; keys[pj] = t; }
            }
            { const int pk = pr - 1; u64_t t = keys[pi]; keys[pi] = keys[pk]; keys[pk] = t; }
            if (pi - pl < pr - pi) { stack[sp++] = pi + 1; stack[sp++] = pr;     pr = pi - 1; }
            else                   { stack[sp++] = pl;     stack[sp++] = pi - 1; pl = pi + 1; }
        }
        const int n = pr - pl + 1;
        if (n >= 2) {
            u64_t nk[16], pay[16];
#pragma unroll
            for (int j = 0; j < 16; ++j) {
                if (j < n) {
                    const u64_t k = keys[pl + j];
                    const unsigned vb = (unsigned)(k >> 32);
                    const unsigned mu = (vb & 0x80000000u) ? ~vb : (vb | 0x80000000u);
                    nk[j]  = ((u64_t)(~mu) << 32) | (unsigned)j;
                    pay[j] = k;
                } else { nk[j] = ~0ull; pay[j] = 0ull; }
            }
#pragma unroll
            for (int p = 1; p < 16; p <<= 1)
#pragma unroll
                for (int k = p; k >= 1; k >>= 1)
#pragma unroll
                    for (int j = k & (p - 1); j + k < 16; j += 2 * k)
#pragma unroll
                        for (int i = 0; i < k; ++i)
                            if (i + j + k < 16)
                                if (((i + j) / (p * 2)) == ((i + j + k) / (p * 2))) {
                                    const int a = i + j, b = i + j + k;
                                    if (nk[a] > nk[b]) {
                                        u64_t t1 = nk[a]; nk[a] = nk[b]; nk[b] = t1;
                                        u64_t t2 = pay[a]; pay[a] = pay[b]; pay[b] = t2;
                                    }
                                }
#pragma unroll
            for (int j = 0; j < 16; ++j)
                if (j < n) keys[pl + j] = pay[j];
        }
        if (sp == 0) break;
        pr = stack[--sp]; pl = stack[--sp];
    }
}

// ---------------------------------------------------------------------------
// Kernel 0: f32 -> bf16 (RNE) copies of x and W.  Also zeroes the worklist
// counter (stream-ordered before k_refine's atomics).
// ---------------------------------------------------------------------------
__device__ inline unsigned f2b_rne(float f)
{
    const unsigned u = __float_as_uint(f);
    return (u + 0x7FFFu + ((u >> 16) & 1u)) >> 16;
}

__global__ __launch_bounds__(256) void k_prep(const float* __restrict__ x,
                                              const float* __restrict__ Wm,
                                              ushort_t* __restrict__ xb,
                                              ushort_t* __restrict__ wb,
                                              int* __restrict__ wcount)
{
    if (blockIdx.x == 0 && threadIdx.x == 0) *wcount = 0;
    const size_t n1 = (size_t)B_ROWS * D_INN / 4;
    const size_t n2 = (size_t)N_COL * D_INN / 4;
    const size_t stride = (size_t)gridDim.x * blockDim.x;
    for (size_t i = (size_t)blockIdx.x * blockDim.x + threadIdx.x; i < n1 + n2; i += stride) {
        const float4 f = (i < n1) ? reinterpret_cast<const float4*>(x)[i]
                                  : reinterpret_cast<const float4*>(Wm)[i - n1];
        uint2 o;
        o.x = f2b_rne(f.x) | (f2b_rne(f.y) << 16);
        o.y = f2b_rne(f.z) | (f2b_rne(f.w) << 16);
        if (i < n1) reinterpret_cast<uint2*>(xb)[i]      = o;
        else        reinterpret_cast<uint2*>(wb)[i - n1] = o;
    }
}

// ---------------------------------------------------------------------------
// Kernel 1: bf16 MFMA GEMM (shortlist).  128x128 tile, BK=32, 4 waves (2x2),
// staging via global_load_lds width=16 (linear LDS dest == [128][32] layout).
// ---------------------------------------------------------------------------
__global__ __launch_bounds__(256) void k_mfma(const ushort_t* __restrict__ xb,
                                              const ushort_t* __restrict__ wb,
                                              const float* __restrict__ bias,
                                              float* __restrict__ xs, int row0)
{
    __shared__ ushort_t As[128][32];
    __shared__ ushort_t Bs[128][32];
    const int t = threadIdx.x;
    const int bm = blockIdx.x, bn = blockIdx.y;
    const int wid = t >> 6, lane = t & 63;
    const int wm = wid >> 1, wn = wid & 1;
    const int arow0 = row0 + bm * 128;
    const int wrow0 = bn * 128;
    const int l15 = lane & 15, lg = lane >> 4;
    const int sr = lane >> 2;
    const int sc = (lane & 3) * 16;

    f32x4 acc[4][4];
#pragma unroll
    for (int i = 0; i < 4; ++i)
#pragma unroll
        for (int j = 0; j < 4; ++j) acc[i][j] = (f32x4){0.f, 0.f, 0.f, 0.f};

    for (int k0 = 0; k0 < D_INN; k0 += 32) {
#pragma unroll
        for (int e = 0; e < 2; ++e) {
            const int c = wid * 2 + e;
            const char* ga = (const char*)xb +
                (((size_t)(arow0 + c * 16 + sr)) * D_INN + k0) * 2 + sc;
            const char* gb = (const char*)wb +
                (((size_t)(wrow0 + c * 16 + sr)) * D_INN + k0) * 2 + sc;
            __builtin_amdgcn_global_load_lds(
                (const __attribute__((address_space(1))) void*)ga,
                (__attribute__((address_space(3))) void*)((char*)&As[0][0] + c * 1024),
                16, 0, 0);
            __builtin_amdgcn_global_load_lds(
                (const __attribute__((address_space(1))) void*)gb,
                (__attribute__((address_space(3))) void*)((char*)&Bs[0][0] + c * 1024),
                16, 0, 0);
        }
        __syncthreads();
        bf16x8 af[4], bg[4];
#pragma unroll
        for (int i = 0; i < 4; ++i)
            af[i] = __builtin_bit_cast(bf16x8,
                *reinterpret_cast<const uint4*>(&As[wm * 64 + i * 16 + l15][lg * 8]));
#pragma unroll
        for (int j = 0; j < 4; ++j)
            bg[j] = __builtin_bit_cast(bf16x8,
                *reinterpret_cast<const uint4*>(&Bs[wn * 64 + j * 16 + l15][lg * 8]));
#pragma unroll
        for (int i = 0; i < 4; ++i)
#pragma unroll
            for (int j = 0; j < 4; ++j)
                acc[i][j] = __builtin_amdgcn_mfma_f32_16x16x32_bf16(af[i], bg[j], acc[i][j], 0, 0, 0);
        __syncthreads();
    }

#pragma unroll
    for (int i = 0; i < 4; ++i)
#pragma unroll
        for (int j = 0; j < 4; ++j) {
            const int col = wn * 64 + j * 16 + l15;
            const float bj = bias[wrow0 + col];
#pragma unroll
            for (int q = 0; q < 4; ++q) {
                const int rloc = bm * 128 + wm * 64 + i * 16 + lg * 4 + q;
                xs[(size_t)rloc * N_COL + wrow0 + col] = acc[i][j][q] + bj;
            }
        }
}

// ---------------------------------------------------------------------------
// Kernel 2: approx top-6 per (row, head, half).  One block per ROW (4 waves;
// wave w handles halves w, w+4, w+8, w+12) — 16x fewer blocks than before.
// ---------------------------------------------------------------------------
__device__ inline unsigned long long shfl_xor_u64(unsigned long long v, int m)
{
    unsigned lo = __shfl_xor((unsigned)(v & 0xFFFFFFFFull), m, 64);
    unsigned hi = __shfl_xor((unsigned)(v >> 32), m, 64);
    return ((unsigned long long)hi << 32) | lo;
}

__global__ __launch_bounds__(256) void k_top8(const float* __restrict__ xs,
                                              uint2* __restrict__ cand, int row0)
{
    const int r    = blockIdx.x;          // chunk-local row
    const int wid  = threadIdx.x >> 6;
    const int lane = threadIdx.x & 63;

    for (int hh = 0; hh < 4; ++hh) {
        const int h2 = wid + hh * 4;
        const float* src = xs + (size_t)r * N_COL + h2 * P_BASE;

        float v[16];
#pragma unroll
        for (int w = 0; w < 4; ++w) {
            const float4 f = *reinterpret_cast<const float4*>(&src[(lane + w * 64) * 4]);
            v[w * 4 + 0] = f.x; v[w * 4 + 1] = f.y; v[w * 4 + 2] = f.z; v[w * 4 + 3] = f.w;
        }
        uint2* outp = cand + ((size_t)(row0 + r) * 16 + h2) * 8;

        for (int it = 0; it < 6; ++it) {
            unsigned long long best = 0ull;
#pragma unroll
            for (int q = 0; q < 16; ++q) {
                const int col = lane * 4 + (q >> 2) * 256 + (q & 3);
                unsigned ub = __float_as_uint(v[q]);
                ub = (ub & 0x80000000u) ? ~ub : (ub | 0x80000000u);
                const unsigned long long key =
                    ((unsigned long long)ub << 32) | (unsigned)(0xFFFFFFFFu - col);
                if (key > best) best = key;
            }
#pragma unroll
            for (int off = 32; off > 0; off >>= 1) {
                const unsigned long long o = shfl_xor_u64(best, off);
                if (o > best) best = o;
            }
            const int col = (int)(0xFFFFFFFFu - (unsigned)(best & 0xFFFFFFFFull));
            if (lane == 0) outp[it] = make_uint2((unsigned)col, 0u);
            const bool own = (lane == ((col & 255) >> 2));
            const int  qi  = ((col >> 8) << 2) | (col & 3);
#pragma unroll
            for (int q = 0; q < 16; ++q)
                if (own && q == qi) v[q] = -__builtin_inff();
        }
    }
}

// ---------------------------------------------------------------------------
// Kernel 3: exact kc=288 recompute of the 6 shortlisted dots per (row, half),
// float4 loads, bit-identical sequential FMA chain; exact stable-L sort of 6;
// write slots 0..5; push tie-flagged rh onto the compaction worklist.
// ---------------------------------------------------------------------------
__global__ __launch_bounds__(128) void k_refine(const float* __restrict__ x,
                                                const float* __restrict__ Wm,
                                                const float* __restrict__ bias,
                                                uint2* __restrict__ cand,
                                                int* __restrict__ wcount,
                                                int* __restrict__ wlist)
{
    __shared__ float xrow[D_INN];
    __shared__ float sval[96];
    const int row = blockIdx.x;
    const int t   = threadIdx.x;

#pragma unroll
    for (int p = 0; p < 4; ++p)
        *reinterpret_cast<float4*>(&xrow[(t + p * 128) * 4]) =
            *reinterpret_cast<const float4*>(&x[(size_t)row * D_INN + (t + p * 128) * 4]);
    __syncthreads();

    if (t < 96) {
        const int h2 = t / 6, c = t % 6;
        const int col  = (int)cand[((size_t)row * 16 + h2) * 8 + c].x;
        const int wcol = (h2 >> 1) * 2048 + (h2 & 1) * P_BASE + col;
        const float4* wr4 = reinterpret_cast<const float4*>(&Wm[(size_t)wcol * D_INN]);
        const float4* xr4 = reinterpret_cast<const float4*>(xrow);

        float accT = 0.f, accC = 0.f;
        int j4 = 0;
        for (int p = 0; p < 7; ++p) {
#pragma unroll 4
            for (int q = 0; q < 72; ++q, ++j4) {
                const float4 w4 = wr4[j4];
                const float4 x4 = xr4[j4];
                accC = fmaf(x4.x, w4.x, accC);
                accC = fmaf(x4.y, w4.y, accC);
                accC = fmaf(x4.z, w4.z, accC);
                accC = fmaf(x4.w, w4.w, accC);
            }
            accT += accC; accC = 0.f;
        }
#pragma unroll
        for (int q = 0; q < 8; ++q, ++j4) {
            const float4 w4 = wr4[j4];
            const float4 x4 = xr4[j4];
            accC = fmaf(x4.x, w4.x, accC);
            accC = fmaf(x4.y, w4.y, accC);
            accC = fmaf(x4.z, w4.z, accC);
            accC = fmaf(x4.w, w4.w, accC);
        }
        accT += accC;
        sval[t] = accT + bias[wcol];
    }
    __syncthreads();

    if (t < 16) {
        float v[6]; int cl[6];
        for (int s = 0; s < 6; ++s) {
            v[s]  = sval[t * 6 + s];
            cl[s] = (int)cand[((size_t)row * 16 + t) * 8 + s].x;
        }
        for (int a = 0; a < 6; ++a) {
            int b = a;
            for (int q = a + 1; q < 6; ++q)
                if (v[q] > v[b] || (v[q] == v[b] && cl[q] < cl[b])) b = q;
            float tv = v[a]; v[a] = v[b]; v[b] = tv;
            int   tc = cl[a]; cl[a] = cl[b]; cl[b] = tc;
        }
        uint2* outp = &cand[((size_t)row * 16 + t) * 8];
        int flag = 0;
        for (int s = 0; s < 6; ++s) outp[s] = make_uint2((unsigned)cl[s], __float_as_uint(v[s]));
        for (int s = 0; s < 4; ++s)
            if (__float_as_uint(v[s]) == __float_as_uint(v[s + 1])) flag = 1;
        if (flag) {
            const int slot = atomicAdd(wcount, 1);
            wlist[slot] = row * 16 + t;
        }
    }
}

// ---------------------------------------------------------------------------
// Kernel 3b: grid-strided over the compacted worklist (fixed 512 blocks):
// exact 1024 dots (1 col/thread, float4+unroll) + exact introsort; top-4.
// ---------------------------------------------------------------------------
__global__ __launch_bounds__(1024) void k_exact1024(const float* __restrict__ x,
                                                    const float* __restrict__ Wm,
                                                    const float* __restrict__ bias,
                                                    uint2* __restrict__ cand,
                                                    const int* __restrict__ wcount,
                                                    const int* __restrict__ wlist)
{
    __shared__ float xrow[D_INN];
    __shared__ u64_t keys[P_BASE];
    const int t = threadIdx.x;
    const int n = *wcount;

    for (int w = blockIdx.x; w < n; w += gridDim.x) {
        const int rh  = wlist[w];
        const int row = rh >> 4, h2 = rh & 15;

        if (t < 512)
            *reinterpret_cast<float4*>(&xrow[t * 4]) =
                *reinterpret_cast<const float4*>(&x[(size_t)row * D_INN + t * 4]);
        __syncthreads();

        const int wbase = (h2 >> 1) * 2048 + (h2 & 1) * P_BASE;
        {
            const int col = t;
            const float4* wr4 = reinterpret_cast<const float4*>(&Wm[(size_t)(wbase + col) * D_INN]);
            const float4* xr4 = reinterpret_cast<const float4*>(xrow);
            float accT = 0.f, accC = 0.f;
            int j4 = 0;
            for (int p = 0; p < 7; ++p) {
#pragma unroll 4
                for (int q = 0; q < 72; ++q, ++j4) {
                    const float4 w4 = wr4[j4];
                    const float4 x4 = xr4[j4];
                    accC = fmaf(x4.x, w4.x, accC);
                    accC = fmaf(x4.y, w4.y, accC);
                    accC = fmaf(x4.z, w4.z, accC);
                    accC = fmaf(x4.w, w4.w, accC);
                }
                accT += accC; accC = 0.f;
            }
#pragma unroll
            for (int q = 0; q < 8; ++q, ++j4) {
                const float4 w4 = wr4[j4];
                const float4 x4 = xr4[j4];
                accC = fmaf(x4.x, w4.x, accC);
                accC = fmaf(x4.y, w4.y, accC);
                accC = fmaf(x4.z, w4.z, accC);
                accC = fmaf(x4.w, w4.w, accC);
            }
            accT += accC;
            const float vv = accT + bias[wbase + col];
            keys[col] = ((u64_t)__float_as_uint(vv) << 32) | (unsigned)col;
        }
        __syncthreads();
        if (t == 0) {
            fast_aqs_desc_1024(keys);
            uint2* outp = &cand[(size_t)rh * 8];
            for (int s = 0; s < 4; ++s) {
                const u64_t k = keys[s];
                outp[s] = make_uint2((unsigned)(k & 0xFFFFFFFFull), (unsigned)(k >> 32));
            }
        }
        __syncthreads();   // protect xrow/keys before next worklist entry
    }
}

// ---------------------------------------------------------------------------
// Kernel 4: per-(row,head) PKM combine (stage-2 stable-L).
// ---------------------------------------------------------------------------
__global__ __launch_bounds__(256) void k_combine(const uint2* __restrict__ cand,
                                                 float* __restrict__ wout,
                                                 int* __restrict__ iout)
{
    const int g = blockIdx.x * 256 + threadIdx.x;
    if (g >= B_ROWS * 8) return;
    const int row = g >> 3, head = g & 7;

    const uint2* c1 = &cand[((size_t)row * 16 + head * 2) * 8];
    const uint2* c2 = c1 + 8;
    float w1[4], w2[4]; int i1[4], i2[4];
#pragma unroll
    for (int a = 0; a < 4; ++a) {
        w1[a] = __uint_as_float(c1[a].y); i1[a] = (int)c1[a].x;
        w2[a] = __uint_as_float(c2[a].y); i2[a] = (int)c2[a].x;
    }
    float cw[16];
#pragma unroll
    for (int a = 0; a < 4; ++a)
#pragma unroll
        for (int b2 = 0; b2 < 4; ++b2) {
            const float s  = w1[a] + w2[b2];
            const float rv = (s > 0.0f) ? s : 0.0f;
            const int   ii = i1[a] * P_BASE + i2[b2];
            cw[a * 4 + b2] = (ii >= L_LAT) ? -1.0f : rv;
        }
    bool used[16];
#pragma unroll
    for (int f = 0; f < 16; ++f) used[f] = false;
    for (int j = 0; j < 4; ++j) {
        int bf = -1;
        for (int f = 0; f < 16; ++f) {
            if (used[f]) continue;
            if (bf < 0 || cw[f] > cw[bf]) bf = f;
        }
        used[bf] = true;
        const int a = bf >> 2, b2 = bf & 3;
        const int ii = i1[a] * P_BASE + i2[b2];
        float wf = cw[bf];
        int ifin;
        if (ii >= L_LAT) { wf = wf * 0.0f; ifin = L_LAT - 1; }
        else             { ifin = ii; }
        wout[((size_t)row * 8 + head) * 4 + j] = wf;
        iout[((size_t)row * 8 + head) * 4 + j] = ifin;
    }
}

// ---------------------------------------------------------------------------
// Kernel 5: stage-3 exact np.argsort(-w32) per row.
// ---------------------------------------------------------------------------
__global__ __launch_bounds__(64) void k_final(const float* __restrict__ wout,
                                              const int* __restrict__ iout,
                                              float* __restrict__ out)
{
    const int row = blockIdx.x * 64 + threadIdx.x;
    if (row >= B_ROWS) return;

    float w[32]; int idx[32]; int tosort[32];
    for (int j = 0; j < 32; ++j) {
        w[j]      = wout[(size_t)row * 32 + j];
        idx[j]    = iout[(size_t)row * 32 + j];
        tosort[j] = j;
    }
    npy_aqs_desc(w, tosort, 32);
    for (int j = 0; j < 32; ++j) {
        const int s = tosort[j];
        out[(size_t)row * 32 + j]                       = w[s];
        out[(size_t)B_ROWS * 32 + (size_t)row * 32 + j] = (float)idx[s];
    }
}

// ---------------------------------------------------------------------------
extern "C" void kernel_launch(void* const* d_in, const int* in_sizes, int n_in,
                              void* d_out, int out_size, void* d_ws, size_t ws_size,
                              hipStream_t stream)
{
    const float* x    = (const float*)d_in[0];
    const float* Wm   = (const float*)d_in[1];
    const float* bias = (const float*)d_in[2];
    float* out = (float*)d_out;

    const size_t xbBytes   = (size_t)B_ROWS * D_INN * 2;
    const size_t wbBytes   = (size_t)N_COL * D_INN * 2;
    const size_t candBytes = (size_t)B_ROWS * 16 * 8 * sizeof(uint2);
    const size_t wlBytes   = (size_t)B_ROWS * 16 * sizeof(int) + 256;   // count + list
    const size_t woutBytes = (size_t)B_ROWS * 32 * sizeof(float);
    const size_t ioutBytes = (size_t)B_ROWS * 32 * sizeof(int);
    const size_t fixedBytes = xbBytes + wbBytes + candBytes + wlBytes + woutBytes + ioutBytes;

    int CH = B_ROWS;
    while (CH > 128 && (size_t)CH * N_COL * sizeof(float) + fixedBytes > ws_size)
        CH >>= 1;

    char*     wsb    = (char*)d_ws;
    float*    xs     = (float*)wsb;
    ushort_t* xb     = (ushort_t*)(wsb + (size_t)CH * N_COL * sizeof(float));
    ushort_t* wb     = (ushort_t*)((char*)xb + xbBytes);
    uint2*    cand   = (uint2*)((char*)wb + wbBytes);
    int*      wcount = (int*)((char*)cand + candBytes);
    int*      wlist  = wcount + 64;   // 256B-aligned region after the counter
    float*    wout   = (float*)((char*)wcount + wlBytes);
    int*      iout   = (int*)((char*)wout + woutBytes);

    k_prep<<<1024, 256, 0, stream>>>(x, Wm, xb, wb, wcount);

    for (int row0 = 0; row0 < B_ROWS; row0 += CH) {
        dim3 grid(CH / 128, N_COL / 128);
        k_mfma<<<grid, 256, 0, stream>>>(xb, wb, bias, xs, row0);
        k_top8<<<CH, 256, 0, stream>>>(xs, cand, row0);
    }
    k_refine<<<B_ROWS, 128, 0, stream>>>(x, Wm, bias, cand, wcount, wlist);
    k_exact1024<<<512, 1024, 0, stream>>>(x, Wm, bias, cand, wcount, wlist);
    k_combine<<<(B_ROWS * 8 + 255) / 256, 256, 0, stream>>>(cand, wout, iout);
    k_final<<<(B_ROWS + 63) / 64, 64, 0, stream>>>(wout, iout, out);
}

// Round 20
// 3256.595 us; speedup vs baseline: 3.4145x; 1.2864x over previous
//
#include <hip/hip_runtime.h>

#define B_ROWS 8192
#define D_INN  2048
#define N_COL  16384
#define P_BASE 1024
#define L_LAT  600000

typedef unsigned short ushort_t;
typedef unsigned long long u64_t;
typedef __attribute__((ext_vector_type(8))) __bf16 bf16x8;
typedef __attribute__((ext_vector_type(4))) float  f32x4;

// ---------------------------------------------------------------------------
// numpy aquicksort (introsort, argsort variant) with LT(a,b) := (b<a):
// exactly np.argsort(-x).  Scalar version (used for the 32-element stage-3).
// ---------------------------------------------------------------------------
#define NPY_LT(a, b) ((b) < (a))
__device__ void npy_aqs_desc(const float* __restrict__ v, int* tosort, int n)
{
    const int SMALL = 15;
    int stack[64]; int sp = 0;
    int pl = 0, pr = n - 1;
    for (;;) {
        while (pr - pl > SMALL) {
            const int pm = pl + ((pr - pl) >> 1);
            if (NPY_LT(v[tosort[pm]], v[tosort[pl]])) { int t = tosort[pm]; tosort[pm] = tosort[pl]; tosort[pl] = t; }
            if (NPY_LT(v[tosort[pr]], v[tosort[pm]])) { int t = tosort[pr]; tosort[pr] = tosort[pm]; tosort[pm] = t; }
            if (NPY_LT(v[tosort[pm]], v[tosort[pl]])) { int t = tosort[pm]; tosort[pm] = tosort[pl]; tosort[pl] = t; }
            const float vp = v[tosort[pm]];
            int pi = pl;
            int pj = pr - 1;
            { int t = tosort[pm]; tosort[pm] = tosort[pj]; tosort[pj] = t; }
            for (;;) {
                do { ++pi; } while (NPY_LT(v[tosort[pi]], vp));
                do { --pj; } while (NPY_LT(vp, v[tosort[pj]]));
                if (pi >= pj) break;
                int t = tosort[pi]; tosort[pi] = tosort[pj]; tosort[pj] = t;
            }
            const int pk = pr - 1;
            { int t = tosort[pi]; tosort[pi] = tosort[pk]; tosort[pk] = t; }
            if (pi - pl < pr - pi) { stack[sp++] = pi + 1; stack[sp++] = pr;     pr = pi - 1; }
            else                   { stack[sp++] = pl;     stack[sp++] = pi - 1; pl = pi + 1; }
        }
        for (int i = pl + 1; i <= pr; ++i) {
            const int vi = tosort[i];
            const float vp = v[vi];
            int j = i;
            while (j > pl && NPY_LT(vp, v[tosort[j - 1]])) { tosort[j] = tosort[j - 1]; --j; }
            tosort[j] = vi;
        }
        if (sp == 0) break;
        pr = stack[--sp]; pl = stack[--sp];
    }
}

// ---------------------------------------------------------------------------
// PRUNED permutation-exact emulation of np.argsort(-x) on 1024 packed LDS
// keys ((f32 bits)<<32 | idx), correct for output positions 0..3:
//  - spans with pl > 3 can never influence keys[0..3] (partitions only move
//    values within a span) -> discarded, leaving the leftmost chain;
//  - batched 8-wide partition scans (validated r17-r19): no swaps occur
//    mid-scan so LDS state equals the serial view; stop = first fail;
//  - leaves sorted by scalar stable descending insertion directly on LDS
//    (== numpy leaf insertion sort), no register arrays -> no spills.
// ---------------------------------------------------------------------------
__device__ inline float kval(u64_t k) { return __uint_as_float((unsigned)(k >> 32)); }

__device__ void pruned_aqs_desc_1024(u64_t* __restrict__ keys)
{
    const int SMALL = 15;
    int spl[8], spr[8]; int sp = 0;
    int pl = 0, pr = P_BASE - 1;
    for (;;) {
        while (pr - pl > SMALL) {
            const int pm = pl + ((pr - pl) >> 1);
            if (kval(keys[pl]) < kval(keys[pm])) { u64_t t = keys[pm]; keys[pm] = keys[pl]; keys[pl] = t; }
            if (kval(keys[pm]) < kval(keys[pr])) { u64_t t = keys[pr]; keys[pr] = keys[pm]; keys[pm] = t; }
            if (kval(keys[pl]) < kval(keys[pm])) { u64_t t = keys[pm]; keys[pm] = keys[pl]; keys[pl] = t; }
            const float vp = kval(keys[pm]);
            int pi = pl;
            int pj = pr - 1;
            { u64_t t = keys[pm]; keys[pm] = keys[pj]; keys[pj] = t; }
            for (;;) {
                ++pi;
                for (;;) {
                    if (pi + 7 <= P_BASE - 1) {
                        u64_t kk[8];
#pragma unroll
                        for (int z = 0; z < 8; ++z) kk[z] = keys[pi + z];
                        int stop = 8;
#pragma unroll
                        for (int z = 7; z >= 0; --z) if (!(kval(kk[z]) > vp)) stop = z;
                        if (stop < 8) { pi += stop; break; }
                        pi += 8;
                    } else {
                        while (kval(keys[pi]) > vp) ++pi;
                        break;
                    }
                }
                --pj;
                for (;;) {
                    if (pj >= 7) {
                        u64_t kk[8];
#pragma unroll
                        for (int z = 0; z < 8; ++z) kk[z] = keys[pj - z];
                        int stop = 8;
#pragma unroll
                        for (int z = 7; z >= 0; --z) if (!(kval(kk[z]) < vp)) stop = z;
                        if (stop < 8) { pj -= stop; break; }
                        pj -= 8;
                    } else {
                        while (kval(keys[pj]) < vp) --pj;
                        break;
                    }
                }
                if (pi >= pj) break;
                { u64_t t = keys[pi]; keys[pi] = keys[pj]; keys[pj] = t; }
            }
            { const int pk = pr - 1; u64_t t = keys[pi]; keys[pi] = keys[pk]; keys[pk] = t; }
            // npy push-larger/continue-smaller, with dead-span (pl > 3) pruning
            if (pi - pl < pr - pi) {
                // push R=[pi+1,pr], continue L=[pl,pi-1]  (L live: pl<=3)
                if (pi + 1 <= 3) { spl[sp] = pi + 1; spr[sp] = pr; ++sp; }
                pr = pi - 1;
            } else {
                // push L=[pl,pi-1], continue R=[pi+1,pr]
                if (pi + 1 <= 3) { spl[sp] = pl; spr[sp] = pi - 1; ++sp; pl = pi + 1; }
                else             { pr = pi - 1; }   // R dead; continue L directly
            }
        }
        // leaf: stable descending insertion sort on LDS == numpy leaf behavior
        for (int i = pl + 1; i <= pr; ++i) {
            const u64_t k = keys[i];
            const float vp = kval(k);
            int j = i;
            while (j > pl && kval(keys[j - 1]) < vp) { keys[j] = keys[j - 1]; --j; }
            keys[j] = k;
        }
        if (sp == 0) break;
        --sp; pl = spl[sp]; pr = spr[sp];
    }
}

// ---------------------------------------------------------------------------
// Kernel 0: f32 -> bf16 (RNE) copies of x and W.  Also zeroes the worklist
// counter (stream-ordered before k_refine's atomics).
// ---------------------------------------------------------------------------
__device__ inline unsigned f2b_rne(float f)
{
    const unsigned u = __float_as_uint(f);
    return (u + 0x7FFFu + ((u >> 16) & 1u)) >> 16;
}

__global__ __launch_bounds__(256) void k_prep(const float* __restrict__ x,
                                              const float* __restrict__ Wm,
                                              ushort_t* __restrict__ xb,
                                              ushort_t* __restrict__ wb,
                                              int* __restrict__ wcount)
{
    if (blockIdx.x == 0 && threadIdx.x == 0) *wcount = 0;
    const size_t n1 = (size_t)B_ROWS * D_INN / 4;
    const size_t n2 = (size_t)N_COL * D_INN / 4;
    const size_t stride = (size_t)gridDim.x * blockDim.x;
    for (size_t i = (size_t)blockIdx.x * blockDim.x + threadIdx.x; i < n1 + n2; i += stride) {
        const float4 f = (i < n1) ? reinterpret_cast<const float4*>(x)[i]
                                  : reinterpret_cast<const float4*>(Wm)[i - n1];
        uint2 o;
        o.x = f2b_rne(f.x) | (f2b_rne(f.y) << 16);
        o.y = f2b_rne(f.z) | (f2b_rne(f.w) << 16);
        if (i < n1) reinterpret_cast<uint2*>(xb)[i]      = o;
        else        reinterpret_cast<uint2*>(wb)[i - n1] = o;
    }
}

// ---------------------------------------------------------------------------
// Kernel 1: bf16 MFMA GEMM (shortlist).  128x128 tile, BK=32, 4 waves (2x2),
// staging via global_load_lds width=16 (linear LDS dest == [128][32] layout).
// ---------------------------------------------------------------------------
__global__ __launch_bounds__(256) void k_mfma(const ushort_t* __restrict__ xb,
                                              const ushort_t* __restrict__ wb,
                                              const float* __restrict__ bias,
                                              float* __restrict__ xs, int row0)
{
    __shared__ ushort_t As[128][32];
    __shared__ ushort_t Bs[128][32];
    const int t = threadIdx.x;
    const int bm = blockIdx.x, bn = blockIdx.y;
    const int wid = t >> 6, lane = t & 63;
    const int wm = wid >> 1, wn = wid & 1;
    const int arow0 = row0 + bm * 128;
    const int wrow0 = bn * 128;
    const int l15 = lane & 15, lg = lane >> 4;
    const int sr = lane >> 2;
    const int sc = (lane & 3) * 16;

    f32x4 acc[4][4];
#pragma unroll
    for (int i = 0; i < 4; ++i)
#pragma unroll
        for (int j = 0; j < 4; ++j) acc[i][j] = (f32x4){0.f, 0.f, 0.f, 0.f};

    for (int k0 = 0; k0 < D_INN; k0 += 32) {
#pragma unroll
        for (int e = 0; e < 2; ++e) {
            const int c = wid * 2 + e;
            const char* ga = (const char*)xb +
                (((size_t)(arow0 + c * 16 + sr)) * D_INN + k0) * 2 + sc;
            const char* gb = (const char*)wb +
                (((size_t)(wrow0 + c * 16 + sr)) * D_INN + k0) * 2 + sc;
            __builtin_amdgcn_global_load_lds(
                (const __attribute__((address_space(1))) void*)ga,
                (__attribute__((address_space(3))) void*)((char*)&As[0][0] + c * 1024),
                16, 0, 0);
            __builtin_amdgcn_global_load_lds(
                (const __attribute__((address_space(1))) void*)gb,
                (__attribute__((address_space(3))) void*)((char*)&Bs[0][0] + c * 1024),
                16, 0, 0);
        }
        __syncthreads();
        bf16x8 af[4], bg[4];
#pragma unroll
        for (int i = 0; i < 4; ++i)
            af[i] = __builtin_bit_cast(bf16x8,
                *reinterpret_cast<const uint4*>(&As[wm * 64 + i * 16 + l15][lg * 8]));
#pragma unroll
        for (int j = 0; j < 4; ++j)
            bg[j] = __builtin_bit_cast(bf16x8,
                *reinterpret_cast<const uint4*>(&Bs[wn * 64 + j * 16 + l15][lg * 8]));
#pragma unroll
        for (int i = 0; i < 4; ++i)
#pragma unroll
            for (int j = 0; j < 4; ++j)
                acc[i][j] = __builtin_amdgcn_mfma_f32_16x16x32_bf16(af[i], bg[j], acc[i][j], 0, 0, 0);
        __syncthreads();
    }

#pragma unroll
    for (int i = 0; i < 4; ++i)
#pragma unroll
        for (int j = 0; j < 4; ++j) {
            const int col = wn * 64 + j * 16 + l15;
            const float bj = bias[wrow0 + col];
#pragma unroll
            for (int q = 0; q < 4; ++q) {
                const int rloc = bm * 128 + wm * 64 + i * 16 + lg * 4 + q;
                xs[(size_t)rloc * N_COL + wrow0 + col] = acc[i][j][q] + bj;
            }
        }
}

// ---------------------------------------------------------------------------
// Kernel 2: approx top-6 per (row, head, half).  One block per ROW (4 waves;
// wave w handles halves w, w+4, w+8, w+12).
// ---------------------------------------------------------------------------
__device__ inline unsigned long long shfl_xor_u64(unsigned long long v, int m)
{
    unsigned lo = __shfl_xor((unsigned)(v & 0xFFFFFFFFull), m, 64);
    unsigned hi = __shfl_xor((unsigned)(v >> 32), m, 64);
    return ((unsigned long long)hi << 32) | lo;
}

__global__ __launch_bounds__(256) void k_top8(const float* __restrict__ xs,
                                              uint2* __restrict__ cand, int row0)
{
    const int r    = blockIdx.x;          // chunk-local row
    const int wid  = threadIdx.x >> 6;
    const int lane = threadIdx.x & 63;

    for (int hh = 0; hh < 4; ++hh) {
        const int h2 = wid + hh * 4;
        const float* src = xs + (size_t)r * N_COL + h2 * P_BASE;

        float v[16];
#pragma unroll
        for (int w = 0; w < 4; ++w) {
            const float4 f = *reinterpret_cast<const float4*>(&src[(lane + w * 64) * 4]);
            v[w * 4 + 0] = f.x; v[w * 4 + 1] = f.y; v[w * 4 + 2] = f.z; v[w * 4 + 3] = f.w;
        }
        uint2* outp = cand + ((size_t)(row0 + r) * 16 + h2) * 8;

        for (int it = 0; it < 6; ++it) {
            unsigned long long best = 0ull;
#pragma unroll
            for (int q = 0; q < 16; ++q) {
                const int col = lane * 4 + (q >> 2) * 256 + (q & 3);
                unsigned ub = __float_as_uint(v[q]);
                ub = (ub & 0x80000000u) ? ~ub : (ub | 0x80000000u);
                const unsigned long long key =
                    ((unsigned long long)ub << 32) | (unsigned)(0xFFFFFFFFu - col);
                if (key > best) best = key;
            }
#pragma unroll
            for (int off = 32; off > 0; off >>= 1) {
                const unsigned long long o = shfl_xor_u64(best, off);
                if (o > best) best = o;
            }
            const int col = (int)(0xFFFFFFFFu - (unsigned)(best & 0xFFFFFFFFull));
            if (lane == 0) outp[it] = make_uint2((unsigned)col, 0u);
            const bool own = (lane == ((col & 255) >> 2));
            const int  qi  = ((col >> 8) << 2) | (col & 3);
#pragma unroll
            for (int q = 0; q < 16; ++q)
                if (own && q == qi) v[q] = -__builtin_inff();
        }
    }
}

// ---------------------------------------------------------------------------
// Kernel 3: exact kc=288 recompute of the 6 shortlisted dots per (row, half),
// float4 loads, bit-identical sequential FMA chain; exact stable-L sort of 6;
// write slots 0..5; push tie-flagged rh onto the compaction worklist.
// ---------------------------------------------------------------------------
__global__ __launch_bounds__(128) void k_refine(const float* __restrict__ x,
                                                const float* __restrict__ Wm,
                                                const float* __restrict__ bias,
                                                uint2* __restrict__ cand,
                                                int* __restrict__ wcount,
                                                int* __restrict__ wlist)
{
    __shared__ float xrow[D_INN];
    __shared__ float sval[96];
    const int row = blockIdx.x;
    const int t   = threadIdx.x;

#pragma unroll
    for (int p = 0; p < 4; ++p)
        *reinterpret_cast<float4*>(&xrow[(t + p * 128) * 4]) =
            *reinterpret_cast<const float4*>(&x[(size_t)row * D_INN + (t + p * 128) * 4]);
    __syncthreads();

    if (t < 96) {
        const int h2 = t / 6, c = t % 6;
        const int col  = (int)cand[((size_t)row * 16 + h2) * 8 + c].x;
        const int wcol = (h2 >> 1) * 2048 + (h2 & 1) * P_BASE + col;
        const float4* wr4 = reinterpret_cast<const float4*>(&Wm[(size_t)wcol * D_INN]);
        const float4* xr4 = reinterpret_cast<const float4*>(xrow);

        float accT = 0.f, accC = 0.f;
        int j4 = 0;
        for (int p = 0; p < 7; ++p) {
#pragma unroll 4
            for (int q = 0; q < 72; ++q, ++j4) {
                const float4 w4 = wr4[j4];
                const float4 x4 = xr4[j4];
                accC = fmaf(x4.x, w4.x, accC);
                accC = fmaf(x4.y, w4.y, accC);
                accC = fmaf(x4.z, w4.z, accC);
                accC = fmaf(x4.w, w4.w, accC);
            }
            accT += accC; accC = 0.f;
        }
#pragma unroll
        for (int q = 0; q < 8; ++q, ++j4) {
            const float4 w4 = wr4[j4];
            const float4 x4 = xr4[j4];
            accC = fmaf(x4.x, w4.x, accC);
            accC = fmaf(x4.y, w4.y, accC);
            accC = fmaf(x4.z, w4.z, accC);
            accC = fmaf(x4.w, w4.w, accC);
        }
        accT += accC;
        sval[t] = accT + bias[wcol];
    }
    __syncthreads();

    if (t < 16) {
        float v[6]; int cl[6];
        for (int s = 0; s < 6; ++s) {
            v[s]  = sval[t * 6 + s];
            cl[s] = (int)cand[((size_t)row * 16 + t) * 8 + s].x;
        }
        for (int a = 0; a < 6; ++a) {
            int b = a;
            for (int q = a + 1; q < 6; ++q)
                if (v[q] > v[b] || (v[q] == v[b] && cl[q] < cl[b])) b = q;
            float tv = v[a]; v[a] = v[b]; v[b] = tv;
            int   tc = cl[a]; cl[a] = cl[b]; cl[b] = tc;
        }
        uint2* outp = &cand[((size_t)row * 16 + t) * 8];
        int flag = 0;
        for (int s = 0; s < 6; ++s) outp[s] = make_uint2((unsigned)cl[s], __float_as_uint(v[s]));
        for (int s = 0; s < 4; ++s)
            if (__float_as_uint(v[s]) == __float_as_uint(v[s + 1])) flag = 1;
        if (flag) {
            const int slot = atomicAdd(wcount, 1);
            wlist[slot] = row * 16 + t;
        }
    }
}

// ---------------------------------------------------------------------------
// Kernel 3b: grid-strided over the compacted worklist: exact 1024 dots
// (1 col/thread, float4+unroll) + PRUNED exact introsort; write top-4.
// ---------------------------------------------------------------------------
__global__ __launch_bounds__(1024) void k_exact1024(const float* __restrict__ x,
                                                    const float* __restrict__ Wm,
                                                    const float* __restrict__ bias,
                                                    uint2* __restrict__ cand,
                                                    const int* __restrict__ wcount,
                                                    const int* __restrict__ wlist)
{
    __shared__ float xrow[D_INN];
    __shared__ u64_t keys[P_BASE];
    const int t = threadIdx.x;
    const int n = *wcount;

    for (int w = blockIdx.x; w < n; w += gridDim.x) {
        const int rh  = wlist[w];
        const int row = rh >> 4, h2 = rh & 15;

        if (t < 512)
            *reinterpret_cast<float4*>(&xrow[t * 4]) =
                *reinterpret_cast<const float4*>(&x[(size_t)row * D_INN + t * 4]);
        __syncthreads();

        const int wbase = (h2 >> 1) * 2048 + (h2 & 1) * P_BASE;
        {
            const int col = t;
            const float4* wr4 = reinterpret_cast<const float4*>(&Wm[(size_t)(wbase + col) * D_INN]);
            const float4* xr4 = reinterpret_cast<const float4*>(xrow);
            float accT = 0.f, accC = 0.f;
            int j4 = 0;
            for (int p = 0; p < 7; ++p) {
#pragma unroll 4
                for (int q = 0; q < 72; ++q, ++j4) {
                    const float4 w4 = wr4[j4];
                    const float4 x4 = xr4[j4];
                    accC = fmaf(x4.x, w4.x, accC);
                    accC = fmaf(x4.y, w4.y, accC);
                    accC = fmaf(x4.z, w4.z, accC);
                    accC = fmaf(x4.w, w4.w, accC);
                }
                accT += accC; accC = 0.f;
            }
#pragma unroll
            for (int q = 0; q < 8; ++q, ++j4) {
                const float4 w4 = wr4[j4];
                const float4 x4 = xr4[j4];
                accC = fmaf(x4.x, w4.x, accC);
                accC = fmaf(x4.y, w4.y, accC);
                accC = fmaf(x4.z, w4.z, accC);
                accC = fmaf(x4.w, w4.w, accC);
            }
            accT += accC;
            const float vv = accT + bias[wbase + col];
            keys[col] = ((u64_t)__float_as_uint(vv) << 32) | (unsigned)col;
        }
        __syncthreads();
        if (t == 0) {
            pruned_aqs_desc_1024(keys);
            uint2* outp = &cand[(size_t)rh * 8];
            for (int s = 0; s < 4; ++s) {
                const u64_t k = keys[s];
                outp[s] = make_uint2((unsigned)(k & 0xFFFFFFFFull), (unsigned)(k >> 32));
            }
        }
        __syncthreads();   // protect xrow/keys before next worklist entry
    }
}

// ---------------------------------------------------------------------------
// Kernel 4: per-(row,head) PKM combine (stage-2 stable-L).
// ---------------------------------------------------------------------------
__global__ __launch_bounds__(256) void k_combine(const uint2* __restrict__ cand,
                                                 float* __restrict__ wout,
                                                 int* __restrict__ iout)
{
    const int g = blockIdx.x * 256 + threadIdx.x;
    if (g >= B_ROWS * 8) return;
    const int row = g >> 3, head = g & 7;

    const uint2* c1 = &cand[((size_t)row * 16 + head * 2) * 8];
    const uint2* c2 = c1 + 8;
    float w1[4], w2[4]; int i1[4], i2[4];
#pragma unroll
    for (int a = 0; a < 4; ++a) {
        w1[a] = __uint_as_float(c1[a].y); i1[a] = (int)c1[a].x;
        w2[a] = __uint_as_float(c2[a].y); i2[a] = (int)c2[a].x;
    }
    float cw[16];
#pragma unroll
    for (int a = 0; a < 4; ++a)
#pragma unroll
        for (int b2 = 0; b2 < 4; ++b2) {
            const float s  = w1[a] + w2[b2];
            const float rv = (s > 0.0f) ? s : 0.0f;
            const int   ii = i1[a] * P_BASE + i2[b2];
            cw[a * 4 + b2] = (ii >= L_LAT) ? -1.0f : rv;
        }
    bool used[16];
#pragma unroll
    for (int f = 0; f < 16; ++f) used[f] = false;
    for (int j = 0; j < 4; ++j) {
        int bf = -1;
        for (int f = 0; f < 16; ++f) {
            if (used[f]) continue;
            if (bf < 0 || cw[f] > cw[bf]) bf = f;
        }
        used[bf] = true;
        const int a = bf >> 2, b2 = bf & 3;
        const int ii = i1[a] * P_BASE + i2[b2];
        float wf = cw[bf];
        int ifin;
        if (ii >= L_LAT) { wf = wf * 0.0f; ifin = L_LAT - 1; }
        else             { ifin = ii; }
        wout[((size_t)row * 8 + head) * 4 + j] = wf;
        iout[((size_t)row * 8 + head) * 4 + j] = ifin;
    }
}

// ---------------------------------------------------------------------------
// Kernel 5: stage-3 exact np.argsort(-w32) per row.
// ---------------------------------------------------------------------------
__global__ __launch_bounds__(64) void k_final(const float* __restrict__ wout,
                                              const int* __restrict__ iout,
                                              float* __restrict__ out)
{
    const int row = blockIdx.x * 64 + threadIdx.x;
    if (row >= B_ROWS) return;

    float w[32]; int idx[32]; int tosort[32];
    for (int j = 0; j < 32; ++j) {
        w[j]      = wout[(size_t)row * 32 + j];
        idx[j]    = iout[(size_t)row * 32 + j];
        tosort[j] = j;
    }
    npy_aqs_desc(w, tosort, 32);
    for (int j = 0; j < 32; ++j) {
        const int s = tosort[j];
        out[(size_t)row * 32 + j]                       = w[s];
        out[(size_t)B_ROWS * 32 + (size_t)row * 32 + j] = (float)idx[s];
    }
}

// ---------------------------------------------------------------------------
extern "C" void kernel_launch(void* const* d_in, const int* in_sizes, int n_in,
                              void* d_out, int out_size, void* d_ws, size_t ws_size,
                              hipStream_t stream)
{
    const float* x    = (const float*)d_in[0];
    const float* Wm   = (const float*)d_in[1];
    const float* bias = (const float*)d_in[2];
    float* out = (float*)d_out;

    const size_t xbBytes   = (size_t)B_ROWS * D_INN * 2;
    const size_t wbBytes   = (size_t)N_COL * D_INN * 2;
    const size_t candBytes = (size_t)B_ROWS * 16 * 8 * sizeof(uint2);
    const size_t wlBytes   = (size_t)B_ROWS * 16 * sizeof(int) + 256;   // count + list
    const size_t woutBytes = (size_t)B_ROWS * 32 * sizeof(float);
    const size_t ioutBytes = (size_t)B_ROWS * 32 * sizeof(int);
    const size_t fixedBytes = xbBytes + wbBytes + candBytes + wlBytes + woutBytes + ioutBytes;

    int CH = B_ROWS;
    while (CH > 128 && (size_t)CH * N_COL * sizeof(float) + fixedBytes > ws_size)
        CH >>= 1;

    char*     wsb    = (char*)d_ws;
    float*    xs     = (float*)wsb;
    ushort_t* xb     = (ushort_t*)(wsb + (size_t)CH * N_COL * sizeof(float));
    ushort_t* wb     = (ushort_t*)((char*)xb + xbBytes);
    uint2*    cand   = (uint2*)((char*)wb + wbBytes);
    int*      wcount = (int*)((char*)cand + candBytes);
    int*      wlist  = wcount + 64;   // 256B-aligned region after the counter
    float*    wout   = (float*)((char*)wcount + wlBytes);
    int*      iout   = (int*)((char*)wout + woutBytes);

    k_prep<<<1024, 256, 0, stream>>>(x, Wm, xb, wb, wcount);

    for (int row0 = 0; row0 < B_ROWS; row0 += CH) {
        dim3 grid(CH / 128, N_COL / 128);
        k_mfma<<<grid, 256, 0, stream>>>(xb, wb, bias, xs, row0);
        k_top8<<<CH, 256, 0, stream>>>(xs, cand, row0);
    }
    k_refine<<<B_ROWS, 128, 0, stream>>>(x, Wm, bias, cand, wcount, wlist);
    k_exact1024<<<512, 1024, 0, stream>>>(x, Wm, bias, cand, wcount, wlist);
    k_combine<<<(B_ROWS * 8 + 255) / 256, 256, 0, stream>>>(cand, wout, iout);
    k_final<<<(B_ROWS + 63) / 64, 64, 0, stream>>>(wout, iout, out);
}

// Round 21
// 3115.350 us; speedup vs baseline: 3.5693x; 1.0453x over previous
//
#include <hip/hip_runtime.h>

#define B_ROWS 8192
#define D_INN  2048
#define N_COL  16384
#define P_BASE 1024
#define L_LAT  600000

typedef unsigned short ushort_t;
typedef unsigned long long u64_t;
typedef __attribute__((ext_vector_type(8))) __bf16 bf16x8;
typedef __attribute__((ext_vector_type(4))) float  f32x4;

// ---------------------------------------------------------------------------
// numpy aquicksort (introsort, argsort variant) with LT(a,b) := (b<a):
// exactly np.argsort(-x).  Scalar version (used for the 32-element stage-3).
// ---------------------------------------------------------------------------
#define NPY_LT(a, b) ((b) < (a))
__device__ void npy_aqs_desc(const float* __restrict__ v, int* tosort, int n)
{
    const int SMALL = 15;
    int stack[64]; int sp = 0;
    int pl = 0, pr = n - 1;
    for (;;) {
        while (pr - pl > SMALL) {
            const int pm = pl + ((pr - pl) >> 1);
            if (NPY_LT(v[tosort[pm]], v[tosort[pl]])) { int t = tosort[pm]; tosort[pm] = tosort[pl]; tosort[pl] = t; }
            if (NPY_LT(v[tosort[pr]], v[tosort[pm]])) { int t = tosort[pr]; tosort[pr] = tosort[pm]; tosort[pm] = t; }
            if (NPY_LT(v[tosort[pm]], v[tosort[pl]])) { int t = tosort[pm]; tosort[pm] = tosort[pl]; tosort[pl] = t; }
            const float vp = v[tosort[pm]];
            int pi = pl;
            int pj = pr - 1;
            { int t = tosort[pm]; tosort[pm] = tosort[pj]; tosort[pj] = t; }
            for (;;) {
                do { ++pi; } while (NPY_LT(v[tosort[pi]], vp));
                do { --pj; } while (NPY_LT(vp, v[tosort[pj]]));
                if (pi >= pj) break;
                int t = tosort[pi]; tosort[pi] = tosort[pj]; tosort[pj] = t;
            }
            const int pk = pr - 1;
            { int t = tosort[pi]; tosort[pi] = tosort[pk]; tosort[pk] = t; }
            if (pi - pl < pr - pi) { stack[sp++] = pi + 1; stack[sp++] = pr;     pr = pi - 1; }
            else                   { stack[sp++] = pl;     stack[sp++] = pi - 1; pl = pi + 1; }
        }
        for (int i = pl + 1; i <= pr; ++i) {
            const int vi = tosort[i];
            const float vp = v[vi];
            int j = i;
            while (j > pl && NPY_LT(vp, v[tosort[j - 1]])) { tosort[j] = tosort[j - 1]; --j; }
            tosort[j] = vi;
        }
        if (sp == 0) break;
        pr = stack[--sp]; pl = stack[--sp];
    }
}

// ---------------------------------------------------------------------------
// PRUNED permutation-exact emulation of np.argsort(-x) on 1024 packed LDS
// keys ((f32 bits)<<32 | idx), correct for output positions 0..3.
// ---------------------------------------------------------------------------
__device__ inline float kval(u64_t k) { return __uint_as_float((unsigned)(k >> 32)); }

__device__ void pruned_aqs_desc_1024(u64_t* __restrict__ keys)
{
    const int SMALL = 15;
    int spl[8], spr[8]; int sp = 0;
    int pl = 0, pr = P_BASE - 1;
    for (;;) {
        while (pr - pl > SMALL) {
            const int pm = pl + ((pr - pl) >> 1);
            if (kval(keys[pl]) < kval(keys[pm])) { u64_t t = keys[pm]; keys[pm] = keys[pl]; keys[pl] = t; }
            if (kval(keys[pm]) < kval(keys[pr])) { u64_t t = keys[pr]; keys[pr] = keys[pm]; keys[pm] = t; }
            if (kval(keys[pl]) < kval(keys[pm])) { u64_t t = keys[pm]; keys[pm] = keys[pl]; keys[pl] = t; }
            const float vp = kval(keys[pm]);
            int pi = pl;
            int pj = pr - 1;
            { u64_t t = keys[pm]; keys[pm] = keys[pj]; keys[pj] = t; }
            for (;;) {
                ++pi;
                for (;;) {
                    if (pi + 7 <= P_BASE - 1) {
                        u64_t kk[8];
#pragma unroll
                        for (int z = 0; z < 8; ++z) kk[z] = keys[pi + z];
                        int stop = 8;
#pragma unroll
                        for (int z = 7; z >= 0; --z) if (!(kval(kk[z]) > vp)) stop = z;
                        if (stop < 8) { pi += stop; break; }
                        pi += 8;
                    } else {
                        while (kval(keys[pi]) > vp) ++pi;
                        break;
                    }
                }
                --pj;
                for (;;) {
                    if (pj >= 7) {
                        u64_t kk[8];
#pragma unroll
                        for (int z = 0; z < 8; ++z) kk[z] = keys[pj - z];
                        int stop = 8;
#pragma unroll
                        for (int z = 7; z >= 0; --z) if (!(kval(kk[z]) < vp)) stop = z;
                        if (stop < 8) { pj -= stop; break; }
                        pj -= 8;
                    } else {
                        while (kval(keys[pj]) < vp) --pj;
                        break;
                    }
                }
                if (pi >= pj) break;
                { u64_t t = keys[pi]; keys[pi] = keys[pj]; keys[pj] = t; }
            }
            { const int pk = pr - 1; u64_t t = keys[pi]; keys[pi] = keys[pk]; keys[pk] = t; }
            if (pi - pl < pr - pi) {
                if (pi + 1 <= 3) { spl[sp] = pi + 1; spr[sp] = pr; ++sp; }
                pr = pi - 1;
            } else {
                if (pi + 1 <= 3) { spl[sp] = pl; spr[sp] = pi - 1; ++sp; pl = pi + 1; }
                else             { pr = pi - 1; }
            }
        }
        for (int i = pl + 1; i <= pr; ++i) {
            const u64_t k = keys[i];
            const float vp = kval(k);
            int j = i;
            while (j > pl && kval(keys[j - 1]) < vp) { keys[j] = keys[j - 1]; --j; }
            keys[j] = k;
        }
        if (sp == 0) break;
        --sp; pl = spl[sp]; pr = spr[sp];
    }
}

// ---------------------------------------------------------------------------
// Kernel 0: f32 -> bf16 (RNE) copies of x and W.  Zeroes worklist counter.
// ---------------------------------------------------------------------------
__device__ inline unsigned f2b_rne(float f)
{
    const unsigned u = __float_as_uint(f);
    return (u + 0x7FFFu + ((u >> 16) & 1u)) >> 16;
}

__global__ __launch_bounds__(256) void k_prep(const float* __restrict__ x,
                                              const float* __restrict__ Wm,
                                              ushort_t* __restrict__ xb,
                                              ushort_t* __restrict__ wb,
                                              int* __restrict__ wcount)
{
    if (blockIdx.x == 0 && threadIdx.x == 0) *wcount = 0;
    const size_t n1 = (size_t)B_ROWS * D_INN / 4;
    const size_t n2 = (size_t)N_COL * D_INN / 4;
    const size_t stride = (size_t)gridDim.x * blockDim.x;
    for (size_t i = (size_t)blockIdx.x * blockDim.x + threadIdx.x; i < n1 + n2; i += stride) {
        const float4 f = (i < n1) ? reinterpret_cast<const float4*>(x)[i]
                                  : reinterpret_cast<const float4*>(Wm)[i - n1];
        uint2 o;
        o.x = f2b_rne(f.x) | (f2b_rne(f.y) << 16);
        o.y = f2b_rne(f.z) | (f2b_rne(f.w) << 16);
        if (i < n1) reinterpret_cast<uint2*>(xb)[i]      = o;
        else        reinterpret_cast<uint2*>(wb)[i - n1] = o;
    }
}

// ---------------------------------------------------------------------------
// Kernel 1: bf16 MFMA GEMM (shortlist).  128x128 tile, BK=32, 4 waves (2x2).
// Staging via global_load_lds width=16 with PRE-SWIZZLED global source
// (chunk q -> q ^ (row&3)); LDS dest stays linear (rule: both-sides-or-
// neither).  Fragment reads XOR the same involution -> identical bytes per
// lane, bank conflict 8-way -> 2-way (free).  1-D grid with bijective
// XCD-chunked remap (bm-fastest per XCD => B panel L2-resident).
// ---------------------------------------------------------------------------
__global__ __launch_bounds__(256) void k_mfma(const ushort_t* __restrict__ xb,
                                              const ushort_t* __restrict__ wb,
                                              const float* __restrict__ bias,
                                              float* __restrict__ xs, int row0,
                                              int nbm)
{
    __shared__ ushort_t As[128][32];
    __shared__ ushort_t Bs[128][32];
    const int t = threadIdx.x;

    // bijective XCD-chunked remap (gridDim.x = nbm*128, divisible by 8)
    const int nwg  = gridDim.x;
    const int q8   = nwg >> 3;
    const int orig = (blockIdx.x & 7) * q8 + (blockIdx.x >> 3);
    const int bm = orig % nbm, bn = orig / nbm;

    const int wid = t >> 6, lane = t & 63;
    const int wm = wid >> 1, wn = wid & 1;
    const int arow0 = row0 + bm * 128;
    const int wrow0 = bn * 128;
    const int l15 = lane & 15, lg = lane >> 4;
    const int sr = lane >> 2;                       // staging row in 16-row chunk
    const int scSw = (((lane & 3) ^ (sr & 3)) * 16); // pre-swizzled source chunk

    f32x4 acc[4][4];
#pragma unroll
    for (int i = 0; i < 4; ++i)
#pragma unroll
        for (int j = 0; j < 4; ++j) acc[i][j] = (f32x4){0.f, 0.f, 0.f, 0.f};

    const int xorA = (l15 & 3) * 8;                 // read-side swizzle (elems)

    for (int k0 = 0; k0 < D_INN; k0 += 32) {
#pragma unroll
        for (int e = 0; e < 2; ++e) {
            const int c = wid * 2 + e;
            const char* ga = (const char*)xb +
                (((size_t)(arow0 + c * 16 + sr)) * D_INN + k0) * 2 + scSw;
            const char* gb = (const char*)wb +
                (((size_t)(wrow0 + c * 16 + sr)) * D_INN + k0) * 2 + scSw;
            __builtin_amdgcn_global_load_lds(
                (const __attribute__((address_space(1))) void*)ga,
                (__attribute__((address_space(3))) void*)((char*)&As[0][0] + c * 1024),
                16, 0, 0);
            __builtin_amdgcn_global_load_lds(
                (const __attribute__((address_space(1))) void*)gb,
                (__attribute__((address_space(3))) void*)((char*)&Bs[0][0] + c * 1024),
                16, 0, 0);
        }
        __syncthreads();
        bf16x8 af[4], bg[4];
#pragma unroll
        for (int i = 0; i < 4; ++i)
            af[i] = __builtin_bit_cast(bf16x8,
                *reinterpret_cast<const uint4*>(&As[wm * 64 + i * 16 + l15][(lg * 8) ^ xorA]));
#pragma unroll
        for (int j = 0; j < 4; ++j)
            bg[j] = __builtin_bit_cast(bf16x8,
                *reinterpret_cast<const uint4*>(&Bs[wn * 64 + j * 16 + l15][(lg * 8) ^ xorA]));
#pragma unroll
        for (int i = 0; i < 4; ++i)
#pragma unroll
            for (int j = 0; j < 4; ++j)
                acc[i][j] = __builtin_amdgcn_mfma_f32_16x16x32_bf16(af[i], bg[j], acc[i][j], 0, 0, 0);
        __syncthreads();
    }

#pragma unroll
    for (int i = 0; i < 4; ++i)
#pragma unroll
        for (int j = 0; j < 4; ++j) {
            const int col = wn * 64 + j * 16 + l15;
            const float bj = bias[wrow0 + col];
#pragma unroll
            for (int q = 0; q < 4; ++q) {
                const int rloc = bm * 128 + wm * 64 + i * 16 + lg * 4 + q;
                xs[(size_t)rloc * N_COL + wrow0 + col] = acc[i][j][q] + bj;
            }
        }
}

// ---------------------------------------------------------------------------
// Kernel 2: approx top-6 per (row, head, half).  One block per ROW (4 waves;
// wave w handles halves w, w+4, w+8, w+12).
// ---------------------------------------------------------------------------
__device__ inline unsigned long long shfl_xor_u64(unsigned long long v, int m)
{
    unsigned lo = __shfl_xor((unsigned)(v & 0xFFFFFFFFull), m, 64);
    unsigned hi = __shfl_xor((unsigned)(v >> 32), m, 64);
    return ((unsigned long long)hi << 32) | lo;
}

__global__ __launch_bounds__(256) void k_top8(const float* __restrict__ xs,
                                              uint2* __restrict__ cand, int row0)
{
    const int r    = blockIdx.x;          // chunk-local row
    const int wid  = threadIdx.x >> 6;
    const int lane = threadIdx.x & 63;

    for (int hh = 0; hh < 4; ++hh) {
        const int h2 = wid + hh * 4;
        const float* src = xs + (size_t)r * N_COL + h2 * P_BASE;

        float v[16];
#pragma unroll
        for (int w = 0; w < 4; ++w) {
            const float4 f = *reinterpret_cast<const float4*>(&src[(lane + w * 64) * 4]);
            v[w * 4 + 0] = f.x; v[w * 4 + 1] = f.y; v[w * 4 + 2] = f.z; v[w * 4 + 3] = f.w;
        }
        uint2* outp = cand + ((size_t)(row0 + r) * 16 + h2) * 8;

        for (int it = 0; it < 6; ++it) {
            unsigned long long best = 0ull;
#pragma unroll
            for (int q = 0; q < 16; ++q) {
                const int col = lane * 4 + (q >> 2) * 256 + (q & 3);
                unsigned ub = __float_as_uint(v[q]);
                ub = (ub & 0x80000000u) ? ~ub : (ub | 0x80000000u);
                const unsigned long long key =
                    ((unsigned long long)ub << 32) | (unsigned)(0xFFFFFFFFu - col);
                if (key > best) best = key;
            }
#pragma unroll
            for (int off = 32; off > 0; off >>= 1) {
                const unsigned long long o = shfl_xor_u64(best, off);
                if (o > best) best = o;
            }
            const int col = (int)(0xFFFFFFFFu - (unsigned)(best & 0xFFFFFFFFull));
            if (lane == 0) outp[it] = make_uint2((unsigned)col, 0u);
            const bool own = (lane == ((col & 255) >> 2));
            const int  qi  = ((col >> 8) << 2) | (col & 3);
#pragma unroll
            for (int q = 0; q < 16; ++q)
                if (own && q == qi) v[q] = -__builtin_inff();
        }
    }
}

// ---------------------------------------------------------------------------
// Kernel 3: exact kc=288 recompute of the 6 shortlisted dots per (row, half),
// float4 loads, bit-identical sequential FMA chain; exact stable-L sort of 6;
// write slots 0..5; push tie-flagged rh onto the compaction worklist.
// ---------------------------------------------------------------------------
__global__ __launch_bounds__(128) void k_refine(const float* __restrict__ x,
                                                const float* __restrict__ Wm,
                                                const float* __restrict__ bias,
                                                uint2* __restrict__ cand,
                                                int* __restrict__ wcount,
                                                int* __restrict__ wlist)
{
    __shared__ float xrow[D_INN];
    __shared__ float sval[96];
    const int row = blockIdx.x;
    const int t   = threadIdx.x;

#pragma unroll
    for (int p = 0; p < 4; ++p)
        *reinterpret_cast<float4*>(&xrow[(t + p * 128) * 4]) =
            *reinterpret_cast<const float4*>(&x[(size_t)row * D_INN + (t + p * 128) * 4]);
    __syncthreads();

    if (t < 96) {
        const int h2 = t / 6, c = t % 6;
        const int col  = (int)cand[((size_t)row * 16 + h2) * 8 + c].x;
        const int wcol = (h2 >> 1) * 2048 + (h2 & 1) * P_BASE + col;
        const float4* wr4 = reinterpret_cast<const float4*>(&Wm[(size_t)wcol * D_INN]);
        const float4* xr4 = reinterpret_cast<const float4*>(xrow);

        float accT = 0.f, accC = 0.f;
        int j4 = 0;
        for (int p = 0; p < 7; ++p) {
#pragma unroll 8
            for (int q = 0; q < 72; ++q, ++j4) {
                const float4 w4 = wr4[j4];
                const float4 x4 = xr4[j4];
                accC = fmaf(x4.x, w4.x, accC);
                accC = fmaf(x4.y, w4.y, accC);
                accC = fmaf(x4.z, w4.z, accC);
                accC = fmaf(x4.w, w4.w, accC);
            }
            accT += accC; accC = 0.f;
        }
#pragma unroll
        for (int q = 0; q < 8; ++q, ++j4) {
            const float4 w4 = wr4[j4];
            const float4 x4 = xr4[j4];
            accC = fmaf(x4.x, w4.x, accC);
            accC = fmaf(x4.y, w4.y, accC);
            accC = fmaf(x4.z, w4.z, accC);
            accC = fmaf(x4.w, w4.w, accC);
        }
        accT += accC;
        sval[t] = accT + bias[wcol];
    }
    __syncthreads();

    if (t < 16) {
        float v[6]; int cl[6];
        for (int s = 0; s < 6; ++s) {
            v[s]  = sval[t * 6 + s];
            cl[s] = (int)cand[((size_t)row * 16 + t) * 8 + s].x;
        }
        for (int a = 0; a < 6; ++a) {
            int b = a;
            for (int q = a + 1; q < 6; ++q)
                if (v[q] > v[b] || (v[q] == v[b] && cl[q] < cl[b])) b = q;
            float tv = v[a]; v[a] = v[b]; v[b] = tv;
            int   tc = cl[a]; cl[a] = cl[b]; cl[b] = tc;
        }
        uint2* outp = &cand[((size_t)row * 16 + t) * 8];
        int flag = 0;
        for (int s = 0; s < 6; ++s) outp[s] = make_uint2((unsigned)cl[s], __float_as_uint(v[s]));
        for (int s = 0; s < 4; ++s)
            if (__float_as_uint(v[s]) == __float_as_uint(v[s + 1])) flag = 1;
        if (flag) {
            const int slot = atomicAdd(wcount, 1);
            wlist[slot] = row * 16 + t;
        }
    }
}

// ---------------------------------------------------------------------------
// Kernel 3b: grid-strided over the compacted worklist: exact 1024 dots
// (1 col/thread, float4+unroll) + PRUNED exact introsort; write top-4.
// ---------------------------------------------------------------------------
__global__ __launch_bounds__(1024) void k_exact1024(const float* __restrict__ x,
                                                    const float* __restrict__ Wm,
                                                    const float* __restrict__ bias,
                                                    uint2* __restrict__ cand,
                                                    const int* __restrict__ wcount,
                                                    const int* __restrict__ wlist)
{
    __shared__ float xrow[D_INN];
    __shared__ u64_t keys[P_BASE];
    const int t = threadIdx.x;
    const int n = *wcount;

    for (int w = blockIdx.x; w < n; w += gridDim.x) {
        const int rh  = wlist[w];
        const int row = rh >> 4, h2 = rh & 15;

        if (t < 512)
            *reinterpret_cast<float4*>(&xrow[t * 4]) =
                *reinterpret_cast<const float4*>(&x[(size_t)row * D_INN + t * 4]);
        __syncthreads();

        const int wbase = (h2 >> 1) * 2048 + (h2 & 1) * P_BASE;
        {
            const int col = t;
            const float4* wr4 = reinterpret_cast<const float4*>(&Wm[(size_t)(wbase + col) * D_INN]);
            const float4* xr4 = reinterpret_cast<const float4*>(xrow);
            float accT = 0.f, accC = 0.f;
            int j4 = 0;
            for (int p = 0; p < 7; ++p) {
#pragma unroll 4
                for (int q = 0; q < 72; ++q, ++j4) {
                    const float4 w4 = wr4[j4];
                    const float4 x4 = xr4[j4];
                    accC = fmaf(x4.x, w4.x, accC);
                    accC = fmaf(x4.y, w4.y, accC);
                    accC = fmaf(x4.z, w4.z, accC);
                    accC = fmaf(x4.w, w4.w, accC);
                }
                accT += accC; accC = 0.f;
            }
#pragma unroll
            for (int q = 0; q < 8; ++q, ++j4) {
                const float4 w4 = wr4[j4];
                const float4 x4 = xr4[j4];
                accC = fmaf(x4.x, w4.x, accC);
                accC = fmaf(x4.y, w4.y, accC);
                accC = fmaf(x4.z, w4.z, accC);
                accC = fmaf(x4.w, w4.w, accC);
            }
            accT += accC;
            const float vv = accT + bias[wbase + col];
            keys[col] = ((u64_t)__float_as_uint(vv) << 32) | (unsigned)col;
        }
        __syncthreads();
        if (t == 0) {
            pruned_aqs_desc_1024(keys);
            uint2* outp = &cand[(size_t)rh * 8];
            for (int s = 0; s < 4; ++s) {
                const u64_t k = keys[s];
                outp[s] = make_uint2((unsigned)(k & 0xFFFFFFFFull), (unsigned)(k >> 32));
            }
        }
        __syncthreads();
    }
}

// ---------------------------------------------------------------------------
// Kernel 4: per-(row,head) PKM combine (stage-2 stable-L).
// ---------------------------------------------------------------------------
__global__ __launch_bounds__(256) void k_combine(const uint2* __restrict__ cand,
                                                 float* __restrict__ wout,
                                                 int* __restrict__ iout)
{
    const int g = blockIdx.x * 256 + threadIdx.x;
    if (g >= B_ROWS * 8) return;
    const int row = g >> 3, head = g & 7;

    const uint2* c1 = &cand[((size_t)row * 16 + head * 2) * 8];
    const uint2* c2 = c1 + 8;
    float w1[4], w2[4]; int i1[4], i2[4];
#pragma unroll
    for (int a = 0; a < 4; ++a) {
        w1[a] = __uint_as_float(c1[a].y); i1[a] = (int)c1[a].x;
        w2[a] = __uint_as_float(c2[a].y); i2[a] = (int)c2[a].x;
    }
    float cw[16];
#pragma unroll
    for (int a = 0; a < 4; ++a)
#pragma unroll
        for (int b2 = 0; b2 < 4; ++b2) {
            const float s  = w1[a] + w2[b2];
            const float rv = (s > 0.0f) ? s : 0.0f;
            const int   ii = i1[a] * P_BASE + i2[b2];
            cw[a * 4 + b2] = (ii >= L_LAT) ? -1.0f : rv;
        }
    bool used[16];
#pragma unroll
    for (int f = 0; f < 16; ++f) used[f] = false;
    for (int j = 0; j < 4; ++j) {
        int bf = -1;
        for (int f = 0; f < 16; ++f) {
            if (used[f]) continue;
            if (bf < 0 || cw[f] > cw[bf]) bf = f;
        }
        used[bf] = true;
        const int a = bf >> 2, b2 = bf & 3;
        const int ii = i1[a] * P_BASE + i2[b2];
        float wf = cw[bf];
        int ifin;
        if (ii >= L_LAT) { wf = wf * 0.0f; ifin = L_LAT - 1; }
        else             { ifin = ii; }
        wout[((size_t)row * 8 + head) * 4 + j] = wf;
        iout[((size_t)row * 8 + head) * 4 + j] = ifin;
    }
}

// ---------------------------------------------------------------------------
// Kernel 5: stage-3 exact np.argsort(-w32) per row.
// ---------------------------------------------------------------------------
__global__ __launch_bounds__(64) void k_final(const float* __restrict__ wout,
                                              const int* __restrict__ iout,
                                              float* __restrict__ out)
{
    const int row = blockIdx.x * 64 + threadIdx.x;
    if (row >= B_ROWS) return;

    float w[32]; int idx[32]; int tosort[32];
    for (int j = 0; j < 32; ++j) {
        w[j]      = wout[(size_t)row * 32 + j];
        idx[j]    = iout[(size_t)row * 32 + j];
        tosort[j] = j;
    }
    npy_aqs_desc(w, tosort, 32);
    for (int j = 0; j < 32; ++j) {
        const int s = tosort[j];
        out[(size_t)row * 32 + j]                       = w[s];
        out[(size_t)B_ROWS * 32 + (size_t)row * 32 + j] = (float)idx[s];
    }
}

// ---------------------------------------------------------------------------
extern "C" void kernel_launch(void* const* d_in, const int* in_sizes, int n_in,
                              void* d_out, int out_size, void* d_ws, size_t ws_size,
                              hipStream_t stream)
{
    const float* x    = (const float*)d_in[0];
    const float* Wm   = (const float*)d_in[1];
    const float* bias = (const float*)d_in[2];
    float* out = (float*)d_out;

    const size_t xbBytes   = (size_t)B_ROWS * D_INN * 2;
    const size_t wbBytes   = (size_t)N_COL * D_INN * 2;
    const size_t candBytes = (size_t)B_ROWS * 16 * 8 * sizeof(uint2);
    const size_t wlBytes   = (size_t)B_ROWS * 16 * sizeof(int) + 256;   // count + list
    const size_t woutBytes = (size_t)B_ROWS * 32 * sizeof(float);
    const size_t ioutBytes = (size_t)B_ROWS * 32 * sizeof(int);
    const size_t fixedBytes = xbBytes + wbBytes + candBytes + wlBytes + woutBytes + ioutBytes;

    int CH = B_ROWS;
    while (CH > 128 && (size_t)CH * N_COL * sizeof(float) + fixedBytes > ws_size)
        CH >>= 1;

    char*     wsb    = (char*)d_ws;
    float*    xs     = (float*)wsb;
    ushort_t* xb     = (ushort_t*)(wsb + (size_t)CH * N_COL * sizeof(float));
    ushort_t* wb     = (ushort_t*)((char*)xb + xbBytes);
    uint2*    cand   = (uint2*)((char*)wb + wbBytes);
    int*      wcount = (int*)((char*)cand + candBytes);
    int*      wlist  = wcount + 64;   // 256B-aligned region after the counter
    float*    wout   = (float*)((char*)wcount + wlBytes);
    int*      iout   = (int*)((char*)wout + woutBytes);

    k_prep<<<1024, 256, 0, stream>>>(x, Wm, xb, wb, wcount);

    const int nbm = CH / 128;
    for (int row0 = 0; row0 < B_ROWS; row0 += CH) {
        k_mfma<<<nbm * 128, 256, 0, stream>>>(xb, wb, bias, xs, row0, nbm);
        k_top8<<<CH, 256, 0, stream>>>(xs, cand, row0);
    }
    k_refine<<<B_ROWS, 128, 0, stream>>>(x, Wm, bias, cand, wcount, wlist);
    k_exact1024<<<512, 1024, 0, stream>>>(x, Wm, bias, cand, wcount, wlist);
    k_combine<<<(B_ROWS * 8 + 255) / 256, 256, 0, stream>>>(cand, wout, iout);
    k_final<<<(B_ROWS + 63) / 64, 64, 0, stream>>>(wout, iout, out);
}